// Round 13
// baseline (246.429 us; speedup 1.0000x reference)
//
#include <hip/hip_runtime.h>

#define N_NODES 100000
#define N_EDGES 1600000
#define F_IN 256
#define HD1 128   // HEADS*HID
#define HEADS 8
#define HID 16
#define NC 16
#define NEG_SLOPE 0.2f
#define LOG2E 1.44269504f

// ---- bucketed CSR build params ----
#define BKT_NODES 512
#define NBKT ((N_NODES + BKT_NODES - 1) / BKT_NODES)   // 196
#define P1_EPB 8192
#define P1_BLOCKS ((N_EDGES + P1_EPB - 1) / P1_EPB)    // 196

__device__ __forceinline__ float leaky(float x){ return x > 0.f ? x : NEG_SLOPE * x; }
__device__ __forceinline__ unsigned short f2bf(float f){
    unsigned u = __float_as_uint(f);
    u += 0x7fff + ((u >> 16) & 1);       // round-to-nearest-even
    return (unsigned short)(u >> 16);
}
__device__ __forceinline__ float bf2f(unsigned short s){
    return __uint_as_float((unsigned)s << 16);
}
__device__ __forceinline__ unsigned char f2fp8(float v){
    return (unsigned char)(__builtin_amdgcn_cvt_pk_fp8_f32(v, v, 0, false) & 0xff);
}
// hardware packed fp32->bf16 (RNE), 2 floats -> 1 dword
__device__ __forceinline__ unsigned cvtpk_bf16(float lo, float hi){
    unsigned r;
    asm("v_cvt_pk_bf16_f32 %0, %1, %2" : "=v"(r) : "v"(lo), "v"(hi));
    return r;
}
// async global->LDS, 16B per lane; LDS base must be wave-uniform
__device__ __forceinline__ void gload_lds16(const float* g, float* l){
    __builtin_amdgcn_global_load_lds(
        (const __attribute__((address_space(1))) unsigned int*)g,
        (__attribute__((address_space(3))) unsigned int*)l, 16, 0, 0);
}

typedef __bf16 bf16x8 __attribute__((ext_vector_type(8)));
typedef short short8 __attribute__((ext_vector_type(8)));
typedef float f32x4 __attribute__((ext_vector_type(4)));
typedef float f32x2 __attribute__((ext_vector_type(2)));

// ---------------- CSR build: bucketed, no random global scatter ----------------

__global__ void __launch_bounds__(256) k_p1hist(const int* __restrict__ dst, int* __restrict__ bucketTotal){
    __shared__ int h[NBKT];
    int t = threadIdx.x;
    for (int i = t; i < NBKT; i += 256) h[i] = 0;
    __syncthreads();
    int base = blockIdx.x * P1_EPB;
    int m = min(P1_EPB, N_EDGES - base);
    for (int i = t; i < m; i += 256) atomicAdd(&h[(unsigned)dst[base + i] >> 9], 1);
    __syncthreads();
    for (int i = t; i < NBKT; i += 256) if (h[i]) atomicAdd(&bucketTotal[i], h[i]);
}

__global__ void __launch_bounds__(256) k_p1scan(const int* __restrict__ bucketTotal,
                                                int* __restrict__ bucketBase, int* __restrict__ bucketCursor,
                                                int* __restrict__ off){
    __shared__ int sc[256];
    int t = threadIdx.x;
    int v = (t < NBKT) ? bucketTotal[t] : 0;
    sc[t] = v; __syncthreads();
    for (int o = 1; o < 256; o <<= 1){
        int a = (t >= o) ? sc[t - o] : 0;
        __syncthreads();
        sc[t] += a;
        __syncthreads();
    }
    if (t < NBKT){
        int b = sc[t] - v;         // exclusive
        bucketBase[t] = b;
        bucketCursor[t] = b;
    }
    if (t == 0){ bucketBase[NBKT] = N_EDGES; off[N_NODES] = N_EDGES; }
}

__global__ void __launch_bounds__(256) k_p1bin(const int* __restrict__ src, const int* __restrict__ dst,
                                               int* __restrict__ bucketCursor,
                                               unsigned long long* __restrict__ pairs){
    __shared__ unsigned long long pl[P1_EPB];   // 64 KB
    __shared__ int h[NBKT];                     // hist -> running cursor
    __shared__ int dl[NBKT];                    // global-base minus local-base
    __shared__ int sc[256];
    int t = threadIdx.x;
    for (int i = t; i < NBKT; i += 256) h[i] = 0;
    __syncthreads();
    int base = blockIdx.x * P1_EPB;
    int m = min(P1_EPB, N_EDGES - base);
    for (int i = t; i < m; i += 256) atomicAdd(&h[(unsigned)dst[base + i] >> 9], 1);
    __syncthreads();
    int v = (t < NBKT) ? h[t] : 0;
    sc[t] = v; __syncthreads();
    for (int o = 1; o < 256; o <<= 1){
        int a = (t >= o) ? sc[t - o] : 0;
        __syncthreads();
        sc[t] += a;
        __syncthreads();
    }
    if (t < NBKT){
        int ex = sc[t] - v;                        // local exclusive base
        int gb = v ? atomicAdd(&bucketCursor[t], v) : 0;
        dl[t] = gb - ex;
        h[t] = ex;                                 // reuse as running local cursor
    }
    __syncthreads();
    for (int i = t; i < m; i += 256){
        int d = dst[base + i], s = src[base + i];
        int b = (unsigned)d >> 9;
        int p = atomicAdd(&h[b], 1);
        pl[p] = ((unsigned long long)(unsigned)d << 32) | (unsigned)s;
    }
    __syncthreads();
    for (int i = t; i < m; i += 256){
        unsigned long long pr = pl[i];
        int b = (unsigned)(pr >> 32) >> 9;
        pairs[i + dl[b]] = pr;                     // sequential-run writes
    }
}

__global__ void __launch_bounds__(256) k_p2place(const unsigned long long* __restrict__ pairs,
                                                 const int* __restrict__ bucketBase,
                                                 int* __restrict__ off, int* __restrict__ csr_src){
    __shared__ int degc[BKT_NODES];
    __shared__ int sc2[BKT_NODES];
    int t = threadIdx.x;
    int b = blockIdx.x;
    int node0 = b * BKT_NODES;
    int nmax = min(BKT_NODES, N_NODES - node0);
    int p0 = bucketBase[b], p1 = bucketBase[b + 1];
    int m = p1 - p0;
    for (int i = t; i < BKT_NODES; i += 256) degc[i] = 0;
    __syncthreads();
    for (int i = t; i < m; i += 256){
        int d = (int)(pairs[p0 + i] >> 32) - node0;
        atomicAdd(&degc[d], 1);
    }
    __syncthreads();
    for (int i = t; i < BKT_NODES; i += 256) sc2[i] = degc[i];
    __syncthreads();
    // Hillis-Steele inclusive scan over 512 with 256 threads
    for (int o = 1; o < BKT_NODES; o <<= 1){
        int i0 = t, i1 = t + 256;
        int a0 = (i0 >= o) ? sc2[i0 - o] : 0;
        int a1 = (i1 >= o) ? sc2[i1 - o] : 0;
        __syncthreads();
        sc2[i0] += a0; sc2[i1] += a1;
        __syncthreads();
    }
    for (int i = t; i < BKT_NODES; i += 256){
        int cur = p0 + sc2[i] - degc[i];           // global exclusive offset
        if (i < nmax) off[node0 + i] = cur;
        degc[i] = cur;                              // becomes global cursor
    }
    __syncthreads();
    for (int i = t; i < m; i += 256){
        unsigned long long pr = pairs[p0 + i];
        int d = (int)(pr >> 32) - node0;
        int pos = atomicAdd(&degc[d], 1);
        csr_src[pos] = (int)(unsigned)pr;          // random only within 32KB window
    }
}

// ---------------- W1 -> bf16, transpose + XOR-swizzle ----------------

__global__ void __launch_bounds__(256) k_splitW(const float* __restrict__ W1,
                                                short* __restrict__ WTH){
    int i = blockIdx.x * 256 + threadIdx.x;   // 32768 elems
    if (i >= F_IN * HD1) return;
    int k = i >> 7, n = i & 127;
    int idx = n * 256 + (k ^ ((n & 7) << 3));
    WTH[idx] = (short)f2bf(W1[i]);
}

// ---------------- GEMM1 (MFMA bf16): h1f8 = fp8(feat @ W1) ----------------
// Single-pass 128x128 tile. Full W1 (bf16, 64KB) in LDS; feat staged via
// global_load_lds (async, 2x16KB double buffer, source-side XOR swizzle).
// In-flight bytes bounded by LDS buffer, not VGPRs -> latency hidden.

__device__ __forceinline__ short8 pack8(float4 f0, float4 f1){
    uint4 p;
    p.x = cvtpk_bf16(f0.x, f0.y);
    p.y = cvtpk_bf16(f0.z, f0.w);
    p.z = cvtpk_bf16(f1.x, f1.y);
    p.w = cvtpk_bf16(f1.z, f1.w);
    return __builtin_bit_cast(short8, p);
}

__global__ void __launch_bounds__(256) k_gemm1m(const float* __restrict__ feat,
                                                const short* __restrict__ WTH,
                                                unsigned char* __restrict__ h1f8){
    __shared__ short sWH[F_IN * HD1];   // 64 KB: [n][k^((n&7)<<3)]
    __shared__ float sF[2][4096];       // 2 x 16KB: [row][chunk^ (row&7)], chunk=4 floats
    int t = threadIdx.x;
    // stage full W (bf16)
    {
        const short8* gh = (const short8*)WTH;
        short8* sh = (short8*)sWH;
        for (int i = t; i < 4096; i += 256) sh[i] = gh[i];
    }

    int wid = t >> 6, lane = t & 63;
    int m16 = lane & 15, kg = lane >> 4;
    int rowb = blockIdx.x * 128;

    // per-lane source row/chunk for staging (LDS dest is wave-uniform base; HW adds lane*16)
    int srow = lane >> 3;                    // row within 8-row region
    int scg  = (lane & 7) ^ srow;            // swizzled logical chunk to fetch

    // K-step staging: 16 regions of 8 rows x 32 floats; region = wid*4+i
    auto stage = [&](int ks, int b){
        #pragma unroll
        for (int i = 0; i < 4; i++){
            int reg = wid * 4 + i;
            int grow = rowb + reg * 8 + srow;
            if (grow > N_NODES - 1) grow = N_NODES - 1;
            const float* gp = feat + (size_t)grow * F_IN + ks * 32 + scg * 4;
            gload_lds16(gp, &sF[b][reg * 256]);
        }
    };

    stage(0, 0);
    __syncthreads();                         // drains W-stage + slab 0

    f32x4 acc[2][8];
    #pragma unroll
    for (int a = 0; a < 2; a++)
        #pragma unroll
        for (int c = 0; c < 8; c++)
            acc[a][c] = (f32x4){0.f, 0.f, 0.f, 0.f};

    int rA0 = wid * 32 + m16, rA1 = rA0 + 16;
    int sw = m16 & 7;                        // A-row swizzle selector (same for both frags)

    #pragma unroll
    for (int ks = 0; ks < 8; ks++){
        int b = ks & 1;
        if (ks < 7) stage(ks + 1, b ^ 1);
        const float* fb = sF[b];
        float4 a00 = *(const float4*)(fb + rA0 * 32 + (((2 * kg) ^ sw) << 2));
        float4 a01 = *(const float4*)(fb + rA0 * 32 + (((2 * kg + 1) ^ sw) << 2));
        float4 a10 = *(const float4*)(fb + rA1 * 32 + (((2 * kg) ^ sw) << 2));
        float4 a11 = *(const float4*)(fb + rA1 * 32 + (((2 * kg + 1) ^ sw) << 2));
        bf16x8 AH0 = __builtin_bit_cast(bf16x8, pack8(a00, a01));
        bf16x8 AH1 = __builtin_bit_cast(bf16x8, pack8(a10, a11));
        int kbase = ks * 32 + kg * 8;
        #pragma unroll
        for (int c = 0; c < 8; c++){
            int n = (c << 4) + m16;
            int kk = kbase ^ ((n & 7) << 3);
            bf16x8 bh = __builtin_bit_cast(bf16x8, *(const short8*)(sWH + n * 256 + kk));
            acc[0][c] = __builtin_amdgcn_mfma_f32_16x16x32_bf16(AH0, bh, acc[0][c], 0, 0, 0);
            acc[1][c] = __builtin_amdgcn_mfma_f32_16x16x32_bf16(AH1, bh, acc[1][c], 0, 0, 0);
        }
        __syncthreads();                     // next slab landed; old slab free
    }

    int wrow = rowb + wid * 32;
    #pragma unroll
    for (int rf = 0; rf < 2; rf++){
        #pragma unroll
        for (int c = 0; c < 8; c++){
            #pragma unroll
            for (int r = 0; r < 4; r++){
                int row = wrow + rf * 16 + kg * 4 + r;
                if (row < N_NODES){
                    int col = c * 16 + m16;
                    h1f8[(size_t)row * HD1 + col] = f2fp8(acc[rf][c][r]);
                }
            }
        }
    }
}

// ---------------- el1/er1 from h1f8 (pre-scaled by log2e; el1 bf16, er1 fp32) ----------------

__global__ void __launch_bounds__(256) k_attn1(const unsigned char* __restrict__ h1f8,
                                               const float* __restrict__ al1, const float* __restrict__ ar1,
                                               unsigned short* __restrict__ el1b, float* __restrict__ er1){
    int i = blockIdx.x * 256 + threadIdx.x;
    if (i >= N_NODES * HEADS) return;
    int n = i >> 3, h = i & 7;
    const unsigned* hp = (const unsigned*)(h1f8 + (size_t)n * HD1 + h * HID);
    float pe = 0.f, pr = 0.f;
    #pragma unroll
    for (int j = 0; j < 4; j++){
        unsigned u = hp[j];
        float x0 = __builtin_amdgcn_cvt_f32_fp8(u, 0);
        float x1 = __builtin_amdgcn_cvt_f32_fp8(u, 1);
        float x2 = __builtin_amdgcn_cvt_f32_fp8(u, 2);
        float x3 = __builtin_amdgcn_cvt_f32_fp8(u, 3);
        const float4 a = ((const float4*)(al1 + h * HID))[j];
        const float4 r = ((const float4*)(ar1 + h * HID))[j];
        pe += x0 * a.x + x1 * a.y + x2 * a.z + x3 * a.w;
        pr += x0 * r.x + x1 * r.y + x2 * r.z + x3 * r.w;
    }
    el1b[i] = f2bf(pe * LOG2E);      // leaky(k x)=k leaky(x): exp(leaky(e)) = exp2(leaky(e*log2e))
    er1[i] = pr * LOG2E;
}

// ---------------- Layer-1 aggregation: 1 wave/node, 16 lanes/edge, 4 edges/iter ----------------

__global__ void __launch_bounds__(256) k_agg1(const int* __restrict__ off, const int* __restrict__ csr_src,
                                              const unsigned short* __restrict__ el1b,
                                              const float* __restrict__ er1,
                                              const unsigned char* __restrict__ h1f8,
                                              const float* __restrict__ b1,
                                              unsigned short* __restrict__ x2b){
    int wid = threadIdx.x >> 6, lane = threadIdx.x & 63;
    int n = blockIdx.x * 4 + wid;
    if (n >= N_NODES) return;
    int jb = off[n], je = off[n + 1];
    int sub = lane >> 4;       // edge slot within quad (0..3)
    int q = lane & 15;         // column group: cols q*8 .. q*8+7
    int hh = q >> 1;           // head (2 lanes per head)
    float ern = er1[n * HEADS + hh];
    float a0=0.f,a1=0.f,a2=0.f,a3=0.f,a4=0.f,a5=0.f,a6=0.f,a7=0.f,wsum=0.f;

    #pragma unroll 2
    for (int j = jb; j < je; j += 4){
        int jj = j + sub;
        int jc = (jj < je) ? jj : je - 1;
        int s = csr_src[jc];
        float el = bf2f(el1b[s * HEADS + hh]);
        float wv = (jj < je) ? __builtin_amdgcn_exp2f(leaky(el + ern)) : 0.f;
        wsum += wv;
        uint2 u = *(const uint2*)(h1f8 + (((size_t)s) << 7) + (q << 3));
        f32x2 p0 = __builtin_amdgcn_cvt_pk_f32_fp8(u.x, 0);
        f32x2 p1 = __builtin_amdgcn_cvt_pk_f32_fp8(u.x, 1);
        f32x2 p2 = __builtin_amdgcn_cvt_pk_f32_fp8(u.y, 0);
        f32x2 p3 = __builtin_amdgcn_cvt_pk_f32_fp8(u.y, 1);
        a0 += wv * p0.x; a1 += wv * p0.y;
        a2 += wv * p1.x; a3 += wv * p1.y;
        a4 += wv * p2.x; a5 += wv * p2.y;
        a6 += wv * p3.x; a7 += wv * p3.y;
    }

    // reduce across the 4 edge-slots (lanes differing in bits 4,5)
    a0 += __shfl_xor(a0, 16); a0 += __shfl_xor(a0, 32);
    a1 += __shfl_xor(a1, 16); a1 += __shfl_xor(a1, 32);
    a2 += __shfl_xor(a2, 16); a2 += __shfl_xor(a2, 32);
    a3 += __shfl_xor(a3, 16); a3 += __shfl_xor(a3, 32);
    a4 += __shfl_xor(a4, 16); a4 += __shfl_xor(a4, 32);
    a5 += __shfl_xor(a5, 16); a5 += __shfl_xor(a5, 32);
    a6 += __shfl_xor(a6, 16); a6 += __shfl_xor(a6, 32);
    a7 += __shfl_xor(a7, 16); a7 += __shfl_xor(a7, 32);
    wsum += __shfl_xor(wsum, 16); wsum += __shfl_xor(wsum, 32);

    if (sub == 0){
        float inv = (je > jb) ? 1.f / wsum : 0.f;
        float o0 = a0*inv, o1 = a1*inv, o2 = a2*inv, o3 = a3*inv;
        float o4 = a4*inv, o5 = a5*inv, o6 = a6*inv, o7 = a7*inv;
        float4 bv0 = *(const float4*)(b1 + (q << 3));
        float4 bv1 = *(const float4*)(b1 + (q << 3) + 4);
        o0 += bv0.x; o1 += bv0.y; o2 += bv0.z; o3 += bv0.w;
        o4 += bv1.x; o5 += bv1.y; o6 += bv1.z; o7 += bv1.w;
        o0 = o0 > 0.f ? o0 : __expf(o0) - 1.f;
        o1 = o1 > 0.f ? o1 : __expf(o1) - 1.f;
        o2 = o2 > 0.f ? o2 : __expf(o2) - 1.f;
        o3 = o3 > 0.f ? o3 : __expf(o3) - 1.f;
        o4 = o4 > 0.f ? o4 : __expf(o4) - 1.f;
        o5 = o5 > 0.f ? o5 : __expf(o5) - 1.f;
        o6 = o6 > 0.f ? o6 : __expf(o6) - 1.f;
        o7 = o7 > 0.f ? o7 : __expf(o7) - 1.f;
        uint4 ov;
        ov.x = cvtpk_bf16(o0, o1);
        ov.y = cvtpk_bf16(o2, o3);
        ov.z = cvtpk_bf16(o4, o5);
        ov.w = cvtpk_bf16(o6, o7);
        *(uint4*)(x2b + (size_t)n * HD1 + (q << 3)) = ov;
    }
}

// ---------------- GEMM2: h2b = bf16(x2 @ W2), fused el2/er2 (pre-scaled) ----------------

__global__ void __launch_bounds__(256) k_gemm2(const unsigned short* __restrict__ x2b, const float* __restrict__ W2,
                                               const float* __restrict__ al2, const float* __restrict__ ar2,
                                               unsigned short* __restrict__ h2b, float* __restrict__ el2, float* __restrict__ er2){
    __shared__ float sW[HD1 * NC];   // 8 KB
    __shared__ float sX[16 * HD1];   // 8 KB
    int t = threadIdx.x;
    for (int i = t; i < (HD1 * NC) / 4; i += 256)
        ((float4*)sW)[i] = ((const float4*)W2)[i];
    int r = t >> 4, c = t & 15;
    float a2 = al2[c], r2 = ar2[c];
    for (int g = blockIdx.x; g * 16 < N_NODES; g += gridDim.x){
        int rowb = g * 16;
        __syncthreads();
        {
            ushort4 v = ((const ushort4*)(x2b + (size_t)rowb * HD1))[t * 2];
            ushort4 v2 = ((const ushort4*)(x2b + (size_t)rowb * HD1))[t * 2 + 1];
            float4 f0 = { bf2f(v.x), bf2f(v.y), bf2f(v.z), bf2f(v.w) };
            float4 f1 = { bf2f(v2.x), bf2f(v2.y), bf2f(v2.z), bf2f(v2.w) };
            ((float4*)sX)[t * 2] = f0;
            ((float4*)sX)[t * 2 + 1] = f1;
        }
        __syncthreads();
        float acc = 0.f;
        #pragma unroll 8
        for (int k = 0; k < HD1; k++)
            acc += sX[r * HD1 + k] * sW[k * NC + c];
        int row = rowb + r;
        h2b[row * NC + c] = f2bf(acc);
        float pe = acc * a2, pr = acc * r2;
        #pragma unroll
        for (int d = 1; d < 16; d <<= 1){ pe += __shfl_xor(pe, d); pr += __shfl_xor(pr, d); }
        if (c == 0){ el2[row] = pe * LOG2E; er2[row] = pr * LOG2E; }
    }
}

// ---------------- Layer-2 aggregation + bias + log_softmax ----------------

__global__ void __launch_bounds__(256) k_agg2(const int* __restrict__ off, const int* __restrict__ csr_src,
                                              const float* __restrict__ el2, const float* __restrict__ er2,
                                              const unsigned short* __restrict__ h2b, const float* __restrict__ b2,
                                              float* __restrict__ out){
    int t = threadIdx.x;
    int sub = t >> 4;          // 16 nodes per block
    int c = t & 15;
    int n = blockIdx.x * 16 + sub;
    if (n >= N_NODES) return;
    int jb = off[n], je = off[n + 1];
    float er = er2[n];
    float accA = 0.f, accB = 0.f, wsA = 0.f, wsB = 0.f;
    int j = jb;
    for (; j + 1 < je; j += 2){
        int s0 = csr_src[j];
        int s1 = csr_src[j + 1];
        float w0 = __builtin_amdgcn_exp2f(leaky(el2[s0] + er));
        float w1 = __builtin_amdgcn_exp2f(leaky(el2[s1] + er));
        float v0 = bf2f(h2b[(size_t)s0 * NC + c]);
        float v1 = bf2f(h2b[(size_t)s1 * NC + c]);
        wsA += w0; accA += w0 * v0;
        wsB += w1; accB += w1 * v1;
    }
    if (j < je){
        int s0 = csr_src[j];
        float w0 = __builtin_amdgcn_exp2f(leaky(el2[s0] + er));
        wsA += w0; accA += w0 * bf2f(h2b[(size_t)s0 * NC + c]);
    }
    float acc = accA + accB, wsum = wsA + wsB;
    float o = (je > jb) ? acc / wsum : 0.f;
    o += b2[c];
    // log_softmax over the 16 classes (16-lane group)
    float m = o;
    #pragma unroll
    for (int d = 1; d < 16; d <<= 1) m = fmaxf(m, __shfl_xor(m, d));
    float ex = __expf(o - m);
    #pragma unroll
    for (int d = 1; d < 16; d <<= 1) ex += __shfl_xor(ex, d);
    out[(size_t)n * NC + c] = o - m - __logf(ex);
}

// ---------------- launch ----------------

extern "C" void kernel_launch(void* const* d_in, const int* in_sizes, int n_in,
                              void* d_out, int out_size, void* d_ws, size_t ws_size,
                              hipStream_t stream){
    const float* feat = (const float*)d_in[0];
    const int*   src  = (const int*)d_in[1];
    const int*   dst  = (const int*)d_in[2];
    const float* W1   = (const float*)d_in[3];
    const float* al1  = (const float*)d_in[4];
    const float* ar1  = (const float*)d_in[5];
    const float* b1   = (const float*)d_in[6];
    const float* W2   = (const float*)d_in[7];
    const float* al2  = (const float*)d_in[8];
    const float* ar2  = (const float*)d_in[9];
    const float* b2   = (const float*)d_in[10];
    float* out = (float*)d_out;

    char* w = (char*)d_ws;
    auto alloc = [&](size_t bytes) -> char* {
        char* p = w;
        w += (bytes + 255) & ~(size_t)255;
        return p;
    };
    int*   off      = (int*)alloc((size_t)(N_NODES + 1) * 4);
    int*   csr_src  = (int*)alloc((size_t)N_EDGES * 4);
    unsigned long long* pairs = (unsigned long long*)alloc((size_t)N_EDGES * 8);
    int*   bucketTotal  = (int*)alloc((size_t)(NBKT + 1) * 4);
    int*   bucketBase   = (int*)alloc((size_t)(NBKT + 1) * 4);
    int*   bucketCursor = (int*)alloc((size_t)(NBKT + 1) * 4);
    unsigned char*  h1f8 = (unsigned char*)alloc((size_t)N_NODES * HD1);
    unsigned short* el1b = (unsigned short*)alloc((size_t)N_NODES * HEADS * 2);
    float* er1v    = (float*)alloc((size_t)N_NODES * HEADS * 4);
    unsigned short* x2b = (unsigned short*)alloc((size_t)N_NODES * HD1 * 2);
    unsigned short* h2b = (unsigned short*)alloc((size_t)N_NODES * NC * 2);
    float* el2v    = (float*)alloc((size_t)N_NODES * 4);
    float* er2v    = (float*)alloc((size_t)N_NODES * 4);
    short* WTH     = (short*)alloc((size_t)F_IN * HD1 * 2);

    // CSR build (bucketed two-pass, no random global scatter)
    hipMemsetAsync(bucketTotal, 0, (size_t)(NBKT + 1) * 4, stream);
    k_p1hist<<<P1_BLOCKS, 256, 0, stream>>>(dst, bucketTotal);
    k_p1scan<<<1, 256, 0, stream>>>(bucketTotal, bucketBase, bucketCursor, off);
    k_p1bin<<<P1_BLOCKS, 256, 0, stream>>>(src, dst, bucketCursor, pairs);
    k_p2place<<<NBKT, 256, 0, stream>>>(pairs, bucketBase, off, csr_src);

    // Layer 1 compute
    k_splitW<<<(F_IN * HD1 + 255) / 256, 256, 0, stream>>>(W1, WTH);
    k_gemm1m<<<(N_NODES + 127) / 128, 256, 0, stream>>>(feat, WTH, h1f8);
    k_attn1<<<(N_NODES * HEADS + 255) / 256, 256, 0, stream>>>(h1f8, al1, ar1, el1b, er1v);

    // Layer-1 aggregation
    k_agg1<<<(N_NODES + 3) / 4, 256, 0, stream>>>(off, csr_src, el1b, er1v, h1f8, b1, x2b);

    // Layer 2
    k_gemm2<<<1024, 256, 0, stream>>>(x2b, W2, al2, ar2, h2b, el2v, er2v);
    k_agg2<<<(N_NODES + 15) / 16, 256, 0, stream>>>(off, csr_src, el2v, er2v, h2b, b2, out);
}

// Round 14
// 242.160 us; speedup vs baseline: 1.0176x; 1.0176x over previous
//
#include <hip/hip_runtime.h>

#define N_NODES 100000
#define N_EDGES 1600000
#define F_IN 256
#define HD1 128   // HEADS*HID
#define HEADS 8
#define HID 16
#define NC 16
#define NEG_SLOPE 0.2f
#define LOG2E 1.44269504f

// ---- bucketed CSR build params ----
#define BKT_NODES 512
#define NBKT ((N_NODES + BKT_NODES - 1) / BKT_NODES)   // 196
#define P1_EPB 8192
#define P1_BLOCKS ((N_EDGES + P1_EPB - 1) / P1_EPB)    // 196

__device__ __forceinline__ float leaky(float x){ return x > 0.f ? x : NEG_SLOPE * x; }
__device__ __forceinline__ unsigned short f2bf(float f){
    unsigned u = __float_as_uint(f);
    u += 0x7fff + ((u >> 16) & 1);       // round-to-nearest-even
    return (unsigned short)(u >> 16);
}
__device__ __forceinline__ float bf2f(unsigned short s){
    return __uint_as_float((unsigned)s << 16);
}
__device__ __forceinline__ unsigned char f2fp8(float v){
    return (unsigned char)(__builtin_amdgcn_cvt_pk_fp8_f32(v, v, 0, false) & 0xff);
}
// hardware packed fp32->bf16 (RNE), 2 floats -> 1 dword
__device__ __forceinline__ unsigned cvtpk_bf16(float lo, float hi){
    unsigned r;
    asm("v_cvt_pk_bf16_f32 %0, %1, %2" : "=v"(r) : "v"(lo), "v"(hi));
    return r;
}

typedef __bf16 bf16x8 __attribute__((ext_vector_type(8)));
typedef short short8 __attribute__((ext_vector_type(8)));
typedef float f32x4 __attribute__((ext_vector_type(4)));
typedef float f32x2 __attribute__((ext_vector_type(2)));

// ---------------- CSR build: bucketed, no random global scatter ----------------

__global__ void __launch_bounds__(256) k_p1hist(const int* __restrict__ dst, int* __restrict__ bucketTotal){
    __shared__ int h[NBKT];
    int t = threadIdx.x;
    for (int i = t; i < NBKT; i += 256) h[i] = 0;
    __syncthreads();
    int base = blockIdx.x * P1_EPB;
    int m = min(P1_EPB, N_EDGES - base);
    for (int i = t; i < m; i += 256) atomicAdd(&h[(unsigned)dst[base + i] >> 9], 1);
    __syncthreads();
    for (int i = t; i < NBKT; i += 256) if (h[i]) atomicAdd(&bucketTotal[i], h[i]);
}

__global__ void __launch_bounds__(256) k_p1scan(const int* __restrict__ bucketTotal,
                                                int* __restrict__ bucketBase, int* __restrict__ bucketCursor,
                                                int* __restrict__ off){
    __shared__ int sc[256];
    int t = threadIdx.x;
    int v = (t < NBKT) ? bucketTotal[t] : 0;
    sc[t] = v; __syncthreads();
    for (int o = 1; o < 256; o <<= 1){
        int a = (t >= o) ? sc[t - o] : 0;
        __syncthreads();
        sc[t] += a;
        __syncthreads();
    }
    if (t < NBKT){
        int b = sc[t] - v;         // exclusive
        bucketBase[t] = b;
        bucketCursor[t] = b;
    }
    if (t == 0){ bucketBase[NBKT] = N_EDGES; off[N_NODES] = N_EDGES; }
}

__global__ void __launch_bounds__(256) k_p1bin(const int* __restrict__ src, const int* __restrict__ dst,
                                               int* __restrict__ bucketCursor,
                                               unsigned long long* __restrict__ pairs){
    __shared__ unsigned long long pl[P1_EPB];   // 64 KB
    __shared__ int h[NBKT];                     // hist -> running cursor
    __shared__ int dl[NBKT];                    // global-base minus local-base
    __shared__ int sc[256];
    int t = threadIdx.x;
    for (int i = t; i < NBKT; i += 256) h[i] = 0;
    __syncthreads();
    int base = blockIdx.x * P1_EPB;
    int m = min(P1_EPB, N_EDGES - base);
    for (int i = t; i < m; i += 256) atomicAdd(&h[(unsigned)dst[base + i] >> 9], 1);
    __syncthreads();
    int v = (t < NBKT) ? h[t] : 0;
    sc[t] = v; __syncthreads();
    for (int o = 1; o < 256; o <<= 1){
        int a = (t >= o) ? sc[t - o] : 0;
        __syncthreads();
        sc[t] += a;
        __syncthreads();
    }
    if (t < NBKT){
        int ex = sc[t] - v;                        // local exclusive base
        int gb = v ? atomicAdd(&bucketCursor[t], v) : 0;
        dl[t] = gb - ex;
        h[t] = ex;                                 // reuse as running local cursor
    }
    __syncthreads();
    for (int i = t; i < m; i += 256){
        int d = dst[base + i], s = src[base + i];
        int b = (unsigned)d >> 9;
        int p = atomicAdd(&h[b], 1);
        pl[p] = ((unsigned long long)(unsigned)d << 32) | (unsigned)s;
    }
    __syncthreads();
    for (int i = t; i < m; i += 256){
        unsigned long long pr = pl[i];
        int b = (unsigned)(pr >> 32) >> 9;
        pairs[i + dl[b]] = pr;                     // sequential-run writes
    }
}

__global__ void __launch_bounds__(256) k_p2place(const unsigned long long* __restrict__ pairs,
                                                 const int* __restrict__ bucketBase,
                                                 int* __restrict__ off, int* __restrict__ csr_src){
    __shared__ int degc[BKT_NODES];
    __shared__ int sc2[BKT_NODES];
    int t = threadIdx.x;
    int b = blockIdx.x;
    int node0 = b * BKT_NODES;
    int nmax = min(BKT_NODES, N_NODES - node0);
    int p0 = bucketBase[b], p1 = bucketBase[b + 1];
    int m = p1 - p0;
    for (int i = t; i < BKT_NODES; i += 256) degc[i] = 0;
    __syncthreads();
    for (int i = t; i < m; i += 256){
        int d = (int)(pairs[p0 + i] >> 32) - node0;
        atomicAdd(&degc[d], 1);
    }
    __syncthreads();
    for (int i = t; i < BKT_NODES; i += 256) sc2[i] = degc[i];
    __syncthreads();
    // Hillis-Steele inclusive scan over 512 with 256 threads
    for (int o = 1; o < BKT_NODES; o <<= 1){
        int i0 = t, i1 = t + 256;
        int a0 = (i0 >= o) ? sc2[i0 - o] : 0;
        int a1 = (i1 >= o) ? sc2[i1 - o] : 0;
        __syncthreads();
        sc2[i0] += a0; sc2[i1] += a1;
        __syncthreads();
    }
    for (int i = t; i < BKT_NODES; i += 256){
        int cur = p0 + sc2[i] - degc[i];           // global exclusive offset
        if (i < nmax) off[node0 + i] = cur;
        degc[i] = cur;                              // becomes global cursor
    }
    __syncthreads();
    for (int i = t; i < m; i += 256){
        unsigned long long pr = pairs[p0 + i];
        int d = (int)(pr >> 32) - node0;
        int pos = atomicAdd(&degc[d], 1);
        csr_src[pos] = (int)(unsigned)pr;          // random only within 32KB window
    }
}

// ---------------- W1 -> bf16, transpose + XOR-swizzle ----------------

__global__ void __launch_bounds__(256) k_splitW(const float* __restrict__ W1,
                                                short* __restrict__ WTH){
    int i = blockIdx.x * 256 + threadIdx.x;   // 32768 elems
    if (i >= F_IN * HD1) return;
    int k = i >> 7, n = i & 127;
    int idx = n * 256 + (k ^ ((n & 7) << 3));
    WTH[idx] = (short)f2bf(W1[i]);
}

// ---------------- GEMM1 (MFMA bf16): h1f8 = fp8(feat @ W1), fused el/er ----------------
// R9 structure (proven 60us): 32KB LDS half-W, compiler-scheduled loads.
// Epilogue computes el1/er1 from fp32 acc via 16-lane shuffle reductions.

__device__ __forceinline__ short8 pack8(float4 f0, float4 f1){
    uint4 p;
    p.x = cvtpk_bf16(f0.x, f0.y);
    p.y = cvtpk_bf16(f0.z, f0.w);
    p.z = cvtpk_bf16(f1.x, f1.y);
    p.w = cvtpk_bf16(f1.z, f1.w);
    return __builtin_bit_cast(short8, p);
}

__global__ void __launch_bounds__(256, 4) k_gemm1m(const float* __restrict__ feat,
                                                   const short* __restrict__ WTH,
                                                   const float* __restrict__ al1, const float* __restrict__ ar1,
                                                   unsigned char* __restrict__ h1f8,
                                                   unsigned short* __restrict__ el1b, float* __restrict__ er1){
    __shared__ short sWH[64 * 256];   // 32 KB
    int t = threadIdx.x;
    int ch = blockIdx.y;
    {
        const short8* gh = (const short8*)(WTH + (size_t)ch * 16384);
        short8* sh = (short8*)sWH;
        for (int i = t; i < 2048; i += 256) sh[i] = gh[i];
    }
    __syncthreads();

    int wid = t >> 6, lane = t & 63;
    int m16 = lane & 15, kg = lane >> 4;
    int rowb = blockIdx.x * 128 + wid * 32;

    f32x4 acc[2][4];
    #pragma unroll
    for (int a = 0; a < 2; a++)
        #pragma unroll
        for (int b = 0; b < 4; b++)
            acc[a][b] = (f32x4){0.f, 0.f, 0.f, 0.f};

    int r0 = rowb + m16;       if (r0 > N_NODES - 1) r0 = N_NODES - 1;
    int r1 = rowb + 16 + m16;  if (r1 > N_NODES - 1) r1 = N_NODES - 1;
    const float* fp0 = feat + (size_t)r0 * F_IN;
    const float* fp1 = feat + (size_t)r1 * F_IN;

    #pragma unroll
    for (int ks = 0; ks < 8; ks++){
        int kbase = ks * 32 + kg * 8;
        short8 a0, a1;
        {
            const float4* p = (const float4*)(fp0 + kbase);
            a0 = pack8(p[0], p[1]);
        }
        {
            const float4* p = (const float4*)(fp1 + kbase);
            a1 = pack8(p[0], p[1]);
        }
        bf16x8 AH0 = __builtin_bit_cast(bf16x8, a0);
        bf16x8 AH1 = __builtin_bit_cast(bf16x8, a1);
        #pragma unroll
        for (int c = 0; c < 4; c++){
            int n = (c << 4) + m16;
            int kk = kbase ^ ((n & 7) << 3);
            bf16x8 bh = __builtin_bit_cast(bf16x8, *(const short8*)(sWH + n * 256 + kk));
            acc[0][c] = __builtin_amdgcn_mfma_f32_16x16x32_bf16(AH0, bh, acc[0][c], 0, 0, 0);
            acc[1][c] = __builtin_amdgcn_mfma_f32_16x16x32_bf16(AH1, bh, acc[1][c], 0, 0, 0);
        }
    }

    // h1f8 store
    #pragma unroll
    for (int rf = 0; rf < 2; rf++){
        #pragma unroll
        for (int c = 0; c < 4; c++){
            #pragma unroll
            for (int r = 0; r < 4; r++){
                int row = rowb + rf * 16 + kg * 4 + r;
                if (row < N_NODES){
                    int col = ch * 64 + c * 16 + m16;
                    h1f8[(size_t)row * HD1 + col] = f2fp8(acc[rf][c][r]);
                }
            }
        }
    }

    // fused attn: this block's 4 heads are c=0..3 (head = ch*4+c), d = m16
    float alv[4], arv[4];
    #pragma unroll
    for (int c = 0; c < 4; c++){
        alv[c] = al1[ch * 64 + c * 16 + m16];
        arv[c] = ar1[ch * 64 + c * 16 + m16];
    }
    #pragma unroll
    for (int rf = 0; rf < 2; rf++){
        #pragma unroll
        for (int c = 0; c < 4; c++){
            #pragma unroll
            for (int r = 0; r < 4; r++){
                float v = acc[rf][c][r];
                float pe = v * alv[c];
                float pr = v * arv[c];
                pe += __shfl_xor(pe, 1); pe += __shfl_xor(pe, 2);
                pe += __shfl_xor(pe, 4); pe += __shfl_xor(pe, 8);
                pr += __shfl_xor(pr, 1); pr += __shfl_xor(pr, 2);
                pr += __shfl_xor(pr, 4); pr += __shfl_xor(pr, 8);
                int row = rowb + rf * 16 + kg * 4 + r;
                if (m16 == c && row < N_NODES){
                    el1b[row * HEADS + ch * 4 + c] = f2bf(pe * LOG2E);
                    er1[row * HEADS + ch * 4 + c] = pr * LOG2E;
                }
            }
        }
    }
}

// ---------------- Layer-1 aggregation: 1 wave/node, 16 lanes/edge, 4 edges/iter ----------------

__global__ void __launch_bounds__(256) k_agg1(const int* __restrict__ off, const int* __restrict__ csr_src,
                                              const unsigned short* __restrict__ el1b,
                                              const float* __restrict__ er1,
                                              const unsigned char* __restrict__ h1f8,
                                              const float* __restrict__ b1,
                                              unsigned short* __restrict__ x2b){
    int wid = threadIdx.x >> 6, lane = threadIdx.x & 63;
    int n = blockIdx.x * 4 + wid;
    if (n >= N_NODES) return;
    int jb = off[n], je = off[n + 1];
    int sub = lane >> 4;       // edge slot within quad (0..3)
    int q = lane & 15;         // column group: cols q*8 .. q*8+7
    int hh = q >> 1;           // head (2 lanes per head)
    float ern = er1[n * HEADS + hh];
    float a0=0.f,a1=0.f,a2=0.f,a3=0.f,a4=0.f,a5=0.f,a6=0.f,a7=0.f,wsum=0.f;

    #pragma unroll 4
    for (int j = jb; j < je; j += 4){
        int jj = j + sub;
        int jc = (jj < je) ? jj : je - 1;
        int s = csr_src[jc];
        float el = bf2f(el1b[s * HEADS + hh]);
        float wv = (jj < je) ? __builtin_amdgcn_exp2f(leaky(el + ern)) : 0.f;
        wsum += wv;
        uint2 u = *(const uint2*)(h1f8 + (((size_t)s) << 7) + (q << 3));
        f32x2 p0 = __builtin_amdgcn_cvt_pk_f32_fp8(u.x, 0);
        f32x2 p1 = __builtin_amdgcn_cvt_pk_f32_fp8(u.x, 1);
        f32x2 p2 = __builtin_amdgcn_cvt_pk_f32_fp8(u.y, 0);
        f32x2 p3 = __builtin_amdgcn_cvt_pk_f32_fp8(u.y, 1);
        a0 += wv * p0.x; a1 += wv * p0.y;
        a2 += wv * p1.x; a3 += wv * p1.y;
        a4 += wv * p2.x; a5 += wv * p2.y;
        a6 += wv * p3.x; a7 += wv * p3.y;
    }

    // reduce across the 4 edge-slots (lanes differing in bits 4,5)
    a0 += __shfl_xor(a0, 16); a0 += __shfl_xor(a0, 32);
    a1 += __shfl_xor(a1, 16); a1 += __shfl_xor(a1, 32);
    a2 += __shfl_xor(a2, 16); a2 += __shfl_xor(a2, 32);
    a3 += __shfl_xor(a3, 16); a3 += __shfl_xor(a3, 32);
    a4 += __shfl_xor(a4, 16); a4 += __shfl_xor(a4, 32);
    a5 += __shfl_xor(a5, 16); a5 += __shfl_xor(a5, 32);
    a6 += __shfl_xor(a6, 16); a6 += __shfl_xor(a6, 32);
    a7 += __shfl_xor(a7, 16); a7 += __shfl_xor(a7, 32);
    wsum += __shfl_xor(wsum, 16); wsum += __shfl_xor(wsum, 32);

    if (sub == 0){
        float inv = (je > jb) ? 1.f / wsum : 0.f;
        float o0 = a0*inv, o1 = a1*inv, o2 = a2*inv, o3 = a3*inv;
        float o4 = a4*inv, o5 = a5*inv, o6 = a6*inv, o7 = a7*inv;
        float4 bv0 = *(const float4*)(b1 + (q << 3));
        float4 bv1 = *(const float4*)(b1 + (q << 3) + 4);
        o0 += bv0.x; o1 += bv0.y; o2 += bv0.z; o3 += bv0.w;
        o4 += bv1.x; o5 += bv1.y; o6 += bv1.z; o7 += bv1.w;
        o0 = o0 > 0.f ? o0 : __expf(o0) - 1.f;
        o1 = o1 > 0.f ? o1 : __expf(o1) - 1.f;
        o2 = o2 > 0.f ? o2 : __expf(o2) - 1.f;
        o3 = o3 > 0.f ? o3 : __expf(o3) - 1.f;
        o4 = o4 > 0.f ? o4 : __expf(o4) - 1.f;
        o5 = o5 > 0.f ? o5 : __expf(o5) - 1.f;
        o6 = o6 > 0.f ? o6 : __expf(o6) - 1.f;
        o7 = o7 > 0.f ? o7 : __expf(o7) - 1.f;
        uint4 ov;
        ov.x = cvtpk_bf16(o0, o1);
        ov.y = cvtpk_bf16(o2, o3);
        ov.z = cvtpk_bf16(o4, o5);
        ov.w = cvtpk_bf16(o6, o7);
        *(uint4*)(x2b + (size_t)n * HD1 + (q << 3)) = ov;
    }
}

// ---------------- GEMM2: h2b = bf16(x2 @ W2), fused el2/er2 (pre-scaled) ----------------

__global__ void __launch_bounds__(256) k_gemm2(const unsigned short* __restrict__ x2b, const float* __restrict__ W2,
                                               const float* __restrict__ al2, const float* __restrict__ ar2,
                                               unsigned short* __restrict__ h2b, float* __restrict__ el2, float* __restrict__ er2){
    __shared__ float sW[HD1 * NC];   // 8 KB
    __shared__ float sX[16 * HD1];   // 8 KB
    int t = threadIdx.x;
    for (int i = t; i < (HD1 * NC) / 4; i += 256)
        ((float4*)sW)[i] = ((const float4*)W2)[i];
    int r = t >> 4, c = t & 15;
    float a2 = al2[c], r2 = ar2[c];
    for (int g = blockIdx.x; g * 16 < N_NODES; g += gridDim.x){
        int rowb = g * 16;
        __syncthreads();
        {
            ushort4 v = ((const ushort4*)(x2b + (size_t)rowb * HD1))[t * 2];
            ushort4 v2 = ((const ushort4*)(x2b + (size_t)rowb * HD1))[t * 2 + 1];
            float4 f0 = { bf2f(v.x), bf2f(v.y), bf2f(v.z), bf2f(v.w) };
            float4 f1 = { bf2f(v2.x), bf2f(v2.y), bf2f(v2.z), bf2f(v2.w) };
            ((float4*)sX)[t * 2] = f0;
            ((float4*)sX)[t * 2 + 1] = f1;
        }
        __syncthreads();
        float acc = 0.f;
        #pragma unroll 8
        for (int k = 0; k < HD1; k++)
            acc += sX[r * HD1 + k] * sW[k * NC + c];
        int row = rowb + r;
        h2b[row * NC + c] = f2bf(acc);
        float pe = acc * a2, pr = acc * r2;
        #pragma unroll
        for (int d = 1; d < 16; d <<= 1){ pe += __shfl_xor(pe, d); pr += __shfl_xor(pr, d); }
        if (c == 0){ el2[row] = pe * LOG2E; er2[row] = pr * LOG2E; }
    }
}

// ---------------- Layer-2 aggregation + bias + log_softmax ----------------

__global__ void __launch_bounds__(256) k_agg2(const int* __restrict__ off, const int* __restrict__ csr_src,
                                              const float* __restrict__ el2, const float* __restrict__ er2,
                                              const unsigned short* __restrict__ h2b, const float* __restrict__ b2,
                                              float* __restrict__ out){
    int t = threadIdx.x;
    int sub = t >> 4;          // 16 nodes per block
    int c = t & 15;
    int n = blockIdx.x * 16 + sub;
    if (n >= N_NODES) return;
    int jb = off[n], je = off[n + 1];
    float er = er2[n];
    float accA = 0.f, accB = 0.f, wsA = 0.f, wsB = 0.f;
    int j = jb;
    for (; j + 1 < je; j += 2){
        int s0 = csr_src[j];
        int s1 = csr_src[j + 1];
        float w0 = __builtin_amdgcn_exp2f(leaky(el2[s0] + er));
        float w1 = __builtin_amdgcn_exp2f(leaky(el2[s1] + er));
        float v0 = bf2f(h2b[(size_t)s0 * NC + c]);
        float v1 = bf2f(h2b[(size_t)s1 * NC + c]);
        wsA += w0; accA += w0 * v0;
        wsB += w1; accB += w1 * v1;
    }
    if (j < je){
        int s0 = csr_src[j];
        float w0 = __builtin_amdgcn_exp2f(leaky(el2[s0] + er));
        wsA += w0; accA += w0 * bf2f(h2b[(size_t)s0 * NC + c]);
    }
    float acc = accA + accB, wsum = wsA + wsB;
    float o = (je > jb) ? acc / wsum : 0.f;
    o += b2[c];
    // log_softmax over the 16 classes (16-lane group)
    float m = o;
    #pragma unroll
    for (int d = 1; d < 16; d <<= 1) m = fmaxf(m, __shfl_xor(m, d));
    float ex = __expf(o - m);
    #pragma unroll
    for (int d = 1; d < 16; d <<= 1) ex += __shfl_xor(ex, d);
    out[(size_t)n * NC + c] = o - m - __logf(ex);
}

// ---------------- launch ----------------

extern "C" void kernel_launch(void* const* d_in, const int* in_sizes, int n_in,
                              void* d_out, int out_size, void* d_ws, size_t ws_size,
                              hipStream_t stream){
    const float* feat = (const float*)d_in[0];
    const int*   src  = (const int*)d_in[1];
    const int*   dst  = (const int*)d_in[2];
    const float* W1   = (const float*)d_in[3];
    const float* al1  = (const float*)d_in[4];
    const float* ar1  = (const float*)d_in[5];
    const float* b1   = (const float*)d_in[6];
    const float* W2   = (const float*)d_in[7];
    const float* al2  = (const float*)d_in[8];
    const float* ar2  = (const float*)d_in[9];
    const float* b2   = (const float*)d_in[10];
    float* out = (float*)d_out;

    char* w = (char*)d_ws;
    auto alloc = [&](size_t bytes) -> char* {
        char* p = w;
        w += (bytes + 255) & ~(size_t)255;
        return p;
    };
    int*   off      = (int*)alloc((size_t)(N_NODES + 1) * 4);
    int*   csr_src  = (int*)alloc((size_t)N_EDGES * 4);
    unsigned long long* pairs = (unsigned long long*)alloc((size_t)N_EDGES * 8);
    int*   bucketTotal  = (int*)alloc((size_t)(NBKT + 1) * 4);
    int*   bucketBase   = (int*)alloc((size_t)(NBKT + 1) * 4);
    int*   bucketCursor = (int*)alloc((size_t)(NBKT + 1) * 4);
    unsigned char*  h1f8 = (unsigned char*)alloc((size_t)N_NODES * HD1);
    unsigned short* el1b = (unsigned short*)alloc((size_t)N_NODES * HEADS * 2);
    float* er1v    = (float*)alloc((size_t)N_NODES * HEADS * 4);
    unsigned short* x2b = (unsigned short*)alloc((size_t)N_NODES * HD1 * 2);
    unsigned short* h2b = (unsigned short*)alloc((size_t)N_NODES * NC * 2);
    float* el2v    = (float*)alloc((size_t)N_NODES * 4);
    float* er2v    = (float*)alloc((size_t)N_NODES * 4);
    short* WTH     = (short*)alloc((size_t)F_IN * HD1 * 2);

    // CSR build (bucketed two-pass, no random global scatter)
    hipMemsetAsync(bucketTotal, 0, (size_t)(NBKT + 1) * 4, stream);
    k_p1hist<<<P1_BLOCKS, 256, 0, stream>>>(dst, bucketTotal);
    k_p1scan<<<1, 256, 0, stream>>>(bucketTotal, bucketBase, bucketCursor, off);
    k_p1bin<<<P1_BLOCKS, 256, 0, stream>>>(src, dst, bucketCursor, pairs);
    k_p2place<<<NBKT, 256, 0, stream>>>(pairs, bucketBase, off, csr_src);

    // Layer 1 compute (attn fused into GEMM epilogue)
    k_splitW<<<(F_IN * HD1 + 255) / 256, 256, 0, stream>>>(W1, WTH);
    dim3 g1((N_NODES + 127) / 128, 2);
    k_gemm1m<<<g1, 256, 0, stream>>>(feat, WTH, al1, ar1, h1f8, el1b, er1v);

    // Layer-1 aggregation
    k_agg1<<<(N_NODES + 3) / 4, 256, 0, stream>>>(off, csr_src, el1b, er1v, h1f8, b1, x2b);

    // Layer 2
    k_gemm2<<<1024, 256, 0, stream>>>(x2b, W2, al2, ar2, h2b, el2v, er2v);
    k_agg2<<<(N_NODES + 15) / 16, 256, 0, stream>>>(off, csr_src, el2v, er2v, h2b, b2, out);
}

// Round 15
// 226.669 us; speedup vs baseline: 1.0872x; 1.0683x over previous
//
#include <hip/hip_runtime.h>

#define N_NODES 100000
#define N_EDGES 1600000
#define F_IN 256
#define HD1 128   // HEADS*HID
#define HEADS 8
#define HID 16
#define NC 16
#define NEG_SLOPE 0.2f
#define LOG2E 1.44269504f

// ---- bucketed CSR build params ----
#define BKT_NODES 512
#define NBKT ((N_NODES + BKT_NODES - 1) / BKT_NODES)   // 196
#define P1_EPB 8192
#define P1_BLOCKS ((N_EDGES + P1_EPB - 1) / P1_EPB)    // 196

__device__ __forceinline__ float leaky(float x){ return x > 0.f ? x : NEG_SLOPE * x; }
__device__ __forceinline__ unsigned short f2bf(float f){
    unsigned u = __float_as_uint(f);
    u += 0x7fff + ((u >> 16) & 1);       // round-to-nearest-even
    return (unsigned short)(u >> 16);
}
__device__ __forceinline__ float bf2f(unsigned short s){
    return __uint_as_float((unsigned)s << 16);
}
__device__ __forceinline__ unsigned char f2fp8(float v){
    return (unsigned char)(__builtin_amdgcn_cvt_pk_fp8_f32(v, v, 0, false) & 0xff);
}
// hardware packed fp32->bf16 (RNE), 2 floats -> 1 dword
__device__ __forceinline__ unsigned cvtpk_bf16(float lo, float hi){
    unsigned r;
    asm("v_cvt_pk_bf16_f32 %0, %1, %2" : "=v"(r) : "v"(lo), "v"(hi));
    return r;
}

typedef __bf16 bf16x8 __attribute__((ext_vector_type(8)));
typedef short short8 __attribute__((ext_vector_type(8)));
typedef float f32x4 __attribute__((ext_vector_type(4)));
typedef float f32x2 __attribute__((ext_vector_type(2)));

// ---------------- CSR build: bucketed, no random global scatter ----------------

__global__ void __launch_bounds__(256) k_p1hist(const int* __restrict__ dst, int* __restrict__ bucketTotal){
    __shared__ int h[NBKT];
    int t = threadIdx.x;
    for (int i = t; i < NBKT; i += 256) h[i] = 0;
    __syncthreads();
    int base = blockIdx.x * P1_EPB;
    int m = min(P1_EPB, N_EDGES - base);
    for (int i = t; i < m; i += 256) atomicAdd(&h[(unsigned)dst[base + i] >> 9], 1);
    __syncthreads();
    for (int i = t; i < NBKT; i += 256) if (h[i]) atomicAdd(&bucketTotal[i], h[i]);
}

__global__ void __launch_bounds__(256) k_p1scan(const int* __restrict__ bucketTotal,
                                                int* __restrict__ bucketBase, int* __restrict__ bucketCursor,
                                                int* __restrict__ off){
    __shared__ int sc[256];
    int t = threadIdx.x;
    int v = (t < NBKT) ? bucketTotal[t] : 0;
    sc[t] = v; __syncthreads();
    for (int o = 1; o < 256; o <<= 1){
        int a = (t >= o) ? sc[t - o] : 0;
        __syncthreads();
        sc[t] += a;
        __syncthreads();
    }
    if (t < NBKT){
        int b = sc[t] - v;         // exclusive
        bucketBase[t] = b;
        bucketCursor[t] = b;
    }
    if (t == 0){ bucketBase[NBKT] = N_EDGES; off[N_NODES] = N_EDGES; }
}

__global__ void __launch_bounds__(256) k_p1bin(const int* __restrict__ src, const int* __restrict__ dst,
                                               int* __restrict__ bucketCursor,
                                               unsigned long long* __restrict__ pairs){
    __shared__ unsigned long long pl[P1_EPB];   // 64 KB
    __shared__ int h[NBKT];                     // hist -> running cursor
    __shared__ int dl[NBKT];                    // global-base minus local-base
    __shared__ int sc[256];
    int t = threadIdx.x;
    for (int i = t; i < NBKT; i += 256) h[i] = 0;
    __syncthreads();
    int base = blockIdx.x * P1_EPB;
    int m = min(P1_EPB, N_EDGES - base);
    for (int i = t; i < m; i += 256) atomicAdd(&h[(unsigned)dst[base + i] >> 9], 1);
    __syncthreads();
    int v = (t < NBKT) ? h[t] : 0;
    sc[t] = v; __syncthreads();
    for (int o = 1; o < 256; o <<= 1){
        int a = (t >= o) ? sc[t - o] : 0;
        __syncthreads();
        sc[t] += a;
        __syncthreads();
    }
    if (t < NBKT){
        int ex = sc[t] - v;                        // local exclusive base
        int gb = v ? atomicAdd(&bucketCursor[t], v) : 0;
        dl[t] = gb - ex;
        h[t] = ex;                                 // reuse as running local cursor
    }
    __syncthreads();
    for (int i = t; i < m; i += 256){
        int d = dst[base + i], s = src[base + i];
        int b = (unsigned)d >> 9;
        int p = atomicAdd(&h[b], 1);
        pl[p] = ((unsigned long long)(unsigned)d << 32) | (unsigned)s;
    }
    __syncthreads();
    for (int i = t; i < m; i += 256){
        unsigned long long pr = pl[i];
        int b = (unsigned)(pr >> 32) >> 9;
        pairs[i + dl[b]] = pr;                     // sequential-run writes
    }
}

__global__ void __launch_bounds__(256) k_p2place(const unsigned long long* __restrict__ pairs,
                                                 const int* __restrict__ bucketBase,
                                                 int* __restrict__ off, int* __restrict__ csr_src){
    __shared__ int degc[BKT_NODES];
    __shared__ int sc2[BKT_NODES];
    int t = threadIdx.x;
    int b = blockIdx.x;
    int node0 = b * BKT_NODES;
    int nmax = min(BKT_NODES, N_NODES - node0);
    int p0 = bucketBase[b], p1 = bucketBase[b + 1];
    int m = p1 - p0;
    for (int i = t; i < BKT_NODES; i += 256) degc[i] = 0;
    __syncthreads();
    for (int i = t; i < m; i += 256){
        int d = (int)(pairs[p0 + i] >> 32) - node0;
        atomicAdd(&degc[d], 1);
    }
    __syncthreads();
    for (int i = t; i < BKT_NODES; i += 256) sc2[i] = degc[i];
    __syncthreads();
    // Hillis-Steele inclusive scan over 512 with 256 threads
    for (int o = 1; o < BKT_NODES; o <<= 1){
        int i0 = t, i1 = t + 256;
        int a0 = (i0 >= o) ? sc2[i0 - o] : 0;
        int a1 = (i1 >= o) ? sc2[i1 - o] : 0;
        __syncthreads();
        sc2[i0] += a0; sc2[i1] += a1;
        __syncthreads();
    }
    for (int i = t; i < BKT_NODES; i += 256){
        int cur = p0 + sc2[i] - degc[i];           // global exclusive offset
        if (i < nmax) off[node0 + i] = cur;
        degc[i] = cur;                              // becomes global cursor
    }
    __syncthreads();
    for (int i = t; i < m; i += 256){
        unsigned long long pr = pairs[p0 + i];
        int d = (int)(pr >> 32) - node0;
        int pos = atomicAdd(&degc[d], 1);
        csr_src[pos] = (int)(unsigned)pr;          // random only within 32KB window
    }
}

// ---------------- W1 -> bf16, transpose + XOR-swizzle ----------------

__global__ void __launch_bounds__(256) k_splitW(const float* __restrict__ W1,
                                                short* __restrict__ WTH){
    int i = blockIdx.x * 256 + threadIdx.x;   // 32768 elems
    if (i >= F_IN * HD1) return;
    int k = i >> 7, n = i & 127;
    int idx = n * 256 + (k ^ ((n & 7) << 3));
    WTH[idx] = (short)f2bf(W1[i]);
}

// ---------------- GEMM1 (MFMA bf16): h1f8 = fp8(feat @ W1) ----------------
// Single pass over all 128 cols: full W1 (bf16, 64KB) in LDS -> feat read once
// (halves fetch vs the y=2 split). Compiler-scheduled direct loads (proven best).

__device__ __forceinline__ short8 pack8(float4 f0, float4 f1){
    uint4 p;
    p.x = cvtpk_bf16(f0.x, f0.y);
    p.y = cvtpk_bf16(f0.z, f0.w);
    p.z = cvtpk_bf16(f1.x, f1.y);
    p.w = cvtpk_bf16(f1.z, f1.w);
    return __builtin_bit_cast(short8, p);
}

__global__ void __launch_bounds__(256, 2) k_gemm1m(const float* __restrict__ feat,
                                                   const short* __restrict__ WTH,
                                                   unsigned char* __restrict__ h1f8){
    __shared__ short sWH[F_IN * HD1];   // 64 KB
    int t = threadIdx.x;
    {
        const short8* gh = (const short8*)WTH;
        short8* sh = (short8*)sWH;
        for (int i = t; i < 4096; i += 256) sh[i] = gh[i];
    }
    __syncthreads();

    int wid = t >> 6, lane = t & 63;
    int m16 = lane & 15, kg = lane >> 4;
    int rowb = blockIdx.x * 128 + wid * 32;

    f32x4 acc[2][8];
    #pragma unroll
    for (int a = 0; a < 2; a++)
        #pragma unroll
        for (int b = 0; b < 8; b++)
            acc[a][b] = (f32x4){0.f, 0.f, 0.f, 0.f};

    int r0 = rowb + m16;       if (r0 > N_NODES - 1) r0 = N_NODES - 1;
    int r1 = rowb + 16 + m16;  if (r1 > N_NODES - 1) r1 = N_NODES - 1;
    const float* fp0 = feat + (size_t)r0 * F_IN;
    const float* fp1 = feat + (size_t)r1 * F_IN;

    #pragma unroll
    for (int ks = 0; ks < 8; ks++){
        int kbase = ks * 32 + kg * 8;
        short8 a0, a1;
        {
            const float4* p = (const float4*)(fp0 + kbase);
            a0 = pack8(p[0], p[1]);
        }
        {
            const float4* p = (const float4*)(fp1 + kbase);
            a1 = pack8(p[0], p[1]);
        }
        bf16x8 AH0 = __builtin_bit_cast(bf16x8, a0);
        bf16x8 AH1 = __builtin_bit_cast(bf16x8, a1);
        #pragma unroll
        for (int c = 0; c < 8; c++){
            int n = (c << 4) + m16;
            int kk = kbase ^ ((n & 7) << 3);
            bf16x8 bh = __builtin_bit_cast(bf16x8, *(const short8*)(sWH + n * 256 + kk));
            acc[0][c] = __builtin_amdgcn_mfma_f32_16x16x32_bf16(AH0, bh, acc[0][c], 0, 0, 0);
            acc[1][c] = __builtin_amdgcn_mfma_f32_16x16x32_bf16(AH1, bh, acc[1][c], 0, 0, 0);
        }
    }

    #pragma unroll
    for (int rf = 0; rf < 2; rf++){
        #pragma unroll
        for (int c = 0; c < 8; c++){
            #pragma unroll
            for (int r = 0; r < 4; r++){
                int row = rowb + rf * 16 + kg * 4 + r;
                if (row < N_NODES){
                    int col = c * 16 + m16;
                    h1f8[(size_t)row * HD1 + col] = f2fp8(acc[rf][c][r]);
                }
            }
        }
    }
}

// ---------------- el1/er1 from h1f8 (pre-scaled by log2e; el1 bf16, er1 fp32) ----------------

__global__ void __launch_bounds__(256) k_attn1(const unsigned char* __restrict__ h1f8,
                                               const float* __restrict__ al1, const float* __restrict__ ar1,
                                               unsigned short* __restrict__ el1b, float* __restrict__ er1){
    int i = blockIdx.x * 256 + threadIdx.x;
    if (i >= N_NODES * HEADS) return;
    int n = i >> 3, h = i & 7;
    const unsigned* hp = (const unsigned*)(h1f8 + (size_t)n * HD1 + h * HID);
    float pe = 0.f, pr = 0.f;
    #pragma unroll
    for (int j = 0; j < 4; j++){
        unsigned u = hp[j];
        float x0 = __builtin_amdgcn_cvt_f32_fp8(u, 0);
        float x1 = __builtin_amdgcn_cvt_f32_fp8(u, 1);
        float x2 = __builtin_amdgcn_cvt_f32_fp8(u, 2);
        float x3 = __builtin_amdgcn_cvt_f32_fp8(u, 3);
        const float4 a = ((const float4*)(al1 + h * HID))[j];
        const float4 r = ((const float4*)(ar1 + h * HID))[j];
        pe += x0 * a.x + x1 * a.y + x2 * a.z + x3 * a.w;
        pr += x0 * r.x + x1 * r.y + x2 * r.z + x3 * r.w;
    }
    el1b[i] = f2bf(pe * LOG2E);      // leaky(k x)=k leaky(x): exp(leaky(e)) = exp2(leaky(e*log2e))
    er1[i] = pr * LOG2E;
}

// ---------------- Layer-1 aggregation: 1 wave/node, 16 lanes/edge, 4 edges/iter ----------------

__global__ void __launch_bounds__(256) k_agg1(const int* __restrict__ off, const int* __restrict__ csr_src,
                                              const unsigned short* __restrict__ el1b,
                                              const float* __restrict__ er1,
                                              const unsigned char* __restrict__ h1f8,
                                              const float* __restrict__ b1,
                                              unsigned short* __restrict__ x2b){
    int wid = threadIdx.x >> 6, lane = threadIdx.x & 63;
    int n = blockIdx.x * 4 + wid;
    if (n >= N_NODES) return;
    int jb = off[n], je = off[n + 1];
    int sub = lane >> 4;       // edge slot within quad (0..3)
    int q = lane & 15;         // column group: cols q*8 .. q*8+7
    int hh = q >> 1;           // head (2 lanes per head)
    float ern = er1[n * HEADS + hh];
    float a0=0.f,a1=0.f,a2=0.f,a3=0.f,a4=0.f,a5=0.f,a6=0.f,a7=0.f,wsum=0.f;

    #pragma unroll 4
    for (int j = jb; j < je; j += 4){
        int jj = j + sub;
        int jc = (jj < je) ? jj : je - 1;
        int s = csr_src[jc];
        float el = bf2f(el1b[s * HEADS + hh]);
        float wv = (jj < je) ? __builtin_amdgcn_exp2f(leaky(el + ern)) : 0.f;
        wsum += wv;
        uint2 u = *(const uint2*)(h1f8 + (((size_t)s) << 7) + (q << 3));
        f32x2 p0 = __builtin_amdgcn_cvt_pk_f32_fp8(u.x, 0);
        f32x2 p1 = __builtin_amdgcn_cvt_pk_f32_fp8(u.x, 1);
        f32x2 p2 = __builtin_amdgcn_cvt_pk_f32_fp8(u.y, 0);
        f32x2 p3 = __builtin_amdgcn_cvt_pk_f32_fp8(u.y, 1);
        a0 += wv * p0.x; a1 += wv * p0.y;
        a2 += wv * p1.x; a3 += wv * p1.y;
        a4 += wv * p2.x; a5 += wv * p2.y;
        a6 += wv * p3.x; a7 += wv * p3.y;
    }

    // reduce across the 4 edge-slots (lanes differing in bits 4,5)
    a0 += __shfl_xor(a0, 16); a0 += __shfl_xor(a0, 32);
    a1 += __shfl_xor(a1, 16); a1 += __shfl_xor(a1, 32);
    a2 += __shfl_xor(a2, 16); a2 += __shfl_xor(a2, 32);
    a3 += __shfl_xor(a3, 16); a3 += __shfl_xor(a3, 32);
    a4 += __shfl_xor(a4, 16); a4 += __shfl_xor(a4, 32);
    a5 += __shfl_xor(a5, 16); a5 += __shfl_xor(a5, 32);
    a6 += __shfl_xor(a6, 16); a6 += __shfl_xor(a6, 32);
    a7 += __shfl_xor(a7, 16); a7 += __shfl_xor(a7, 32);
    wsum += __shfl_xor(wsum, 16); wsum += __shfl_xor(wsum, 32);

    if (sub == 0){
        float inv = (je > jb) ? 1.f / wsum : 0.f;
        float o0 = a0*inv, o1 = a1*inv, o2 = a2*inv, o3 = a3*inv;
        float o4 = a4*inv, o5 = a5*inv, o6 = a6*inv, o7 = a7*inv;
        float4 bv0 = *(const float4*)(b1 + (q << 3));
        float4 bv1 = *(const float4*)(b1 + (q << 3) + 4);
        o0 += bv0.x; o1 += bv0.y; o2 += bv0.z; o3 += bv0.w;
        o4 += bv1.x; o5 += bv1.y; o6 += bv1.z; o7 += bv1.w;
        o0 = o0 > 0.f ? o0 : __expf(o0) - 1.f;
        o1 = o1 > 0.f ? o1 : __expf(o1) - 1.f;
        o2 = o2 > 0.f ? o2 : __expf(o2) - 1.f;
        o3 = o3 > 0.f ? o3 : __expf(o3) - 1.f;
        o4 = o4 > 0.f ? o4 : __expf(o4) - 1.f;
        o5 = o5 > 0.f ? o5 : __expf(o5) - 1.f;
        o6 = o6 > 0.f ? o6 : __expf(o6) - 1.f;
        o7 = o7 > 0.f ? o7 : __expf(o7) - 1.f;
        uint4 ov;
        ov.x = cvtpk_bf16(o0, o1);
        ov.y = cvtpk_bf16(o2, o3);
        ov.z = cvtpk_bf16(o4, o5);
        ov.w = cvtpk_bf16(o6, o7);
        *(uint4*)(x2b + (size_t)n * HD1 + (q << 3)) = ov;
    }
}

// ---------------- GEMM2: h2b = bf16(x2 @ W2), fused el2/er2 (pre-scaled) ----------------

__global__ void __launch_bounds__(256) k_gemm2(const unsigned short* __restrict__ x2b, const float* __restrict__ W2,
                                               const float* __restrict__ al2, const float* __restrict__ ar2,
                                               unsigned short* __restrict__ h2b, float* __restrict__ el2, float* __restrict__ er2){
    __shared__ float sW[HD1 * NC];   // 8 KB
    __shared__ float sX[16 * HD1];   // 8 KB
    int t = threadIdx.x;
    for (int i = t; i < (HD1 * NC) / 4; i += 256)
        ((float4*)sW)[i] = ((const float4*)W2)[i];
    int r = t >> 4, c = t & 15;
    float a2 = al2[c], r2 = ar2[c];
    for (int g = blockIdx.x; g * 16 < N_NODES; g += gridDim.x){
        int rowb = g * 16;
        __syncthreads();
        {
            ushort4 v = ((const ushort4*)(x2b + (size_t)rowb * HD1))[t * 2];
            ushort4 v2 = ((const ushort4*)(x2b + (size_t)rowb * HD1))[t * 2 + 1];
            float4 f0 = { bf2f(v.x), bf2f(v.y), bf2f(v.z), bf2f(v.w) };
            float4 f1 = { bf2f(v2.x), bf2f(v2.y), bf2f(v2.z), bf2f(v2.w) };
            ((float4*)sX)[t * 2] = f0;
            ((float4*)sX)[t * 2 + 1] = f1;
        }
        __syncthreads();
        float acc = 0.f;
        #pragma unroll 8
        for (int k = 0; k < HD1; k++)
            acc += sX[r * HD1 + k] * sW[k * NC + c];
        int row = rowb + r;
        h2b[row * NC + c] = f2bf(acc);
        float pe = acc * a2, pr = acc * r2;
        #pragma unroll
        for (int d = 1; d < 16; d <<= 1){ pe += __shfl_xor(pe, d); pr += __shfl_xor(pr, d); }
        if (c == 0){ el2[row] = pe * LOG2E; er2[row] = pr * LOG2E; }
    }
}

// ---------------- Layer-2 aggregation + bias + log_softmax ----------------

__global__ void __launch_bounds__(256) k_agg2(const int* __restrict__ off, const int* __restrict__ csr_src,
                                              const float* __restrict__ el2, const float* __restrict__ er2,
                                              const unsigned short* __restrict__ h2b, const float* __restrict__ b2,
                                              float* __restrict__ out){
    int t = threadIdx.x;
    int sub = t >> 4;          // 16 nodes per block
    int c = t & 15;
    int n = blockIdx.x * 16 + sub;
    if (n >= N_NODES) return;
    int jb = off[n], je = off[n + 1];
    float er = er2[n];
    float accA = 0.f, accB = 0.f, wsA = 0.f, wsB = 0.f;
    int j = jb;
    for (; j + 1 < je; j += 2){
        int s0 = csr_src[j];
        int s1 = csr_src[j + 1];
        float w0 = __builtin_amdgcn_exp2f(leaky(el2[s0] + er));
        float w1 = __builtin_amdgcn_exp2f(leaky(el2[s1] + er));
        float v0 = bf2f(h2b[(size_t)s0 * NC + c]);
        float v1 = bf2f(h2b[(size_t)s1 * NC + c]);
        wsA += w0; accA += w0 * v0;
        wsB += w1; accB += w1 * v1;
    }
    if (j < je){
        int s0 = csr_src[j];
        float w0 = __builtin_amdgcn_exp2f(leaky(el2[s0] + er));
        wsA += w0; accA += w0 * bf2f(h2b[(size_t)s0 * NC + c]);
    }
    float acc = accA + accB, wsum = wsA + wsB;
    float o = (je > jb) ? acc / wsum : 0.f;
    o += b2[c];
    // log_softmax over the 16 classes (16-lane group)
    float m = o;
    #pragma unroll
    for (int d = 1; d < 16; d <<= 1) m = fmaxf(m, __shfl_xor(m, d));
    float ex = __expf(o - m);
    #pragma unroll
    for (int d = 1; d < 16; d <<= 1) ex += __shfl_xor(ex, d);
    out[(size_t)n * NC + c] = o - m - __logf(ex);
}

// ---------------- launch ----------------

extern "C" void kernel_launch(void* const* d_in, const int* in_sizes, int n_in,
                              void* d_out, int out_size, void* d_ws, size_t ws_size,
                              hipStream_t stream){
    const float* feat = (const float*)d_in[0];
    const int*   src  = (const int*)d_in[1];
    const int*   dst  = (const int*)d_in[2];
    const float* W1   = (const float*)d_in[3];
    const float* al1  = (const float*)d_in[4];
    const float* ar1  = (const float*)d_in[5];
    const float* b1   = (const float*)d_in[6];
    const float* W2   = (const float*)d_in[7];
    const float* al2  = (const float*)d_in[8];
    const float* ar2  = (const float*)d_in[9];
    const float* b2   = (const float*)d_in[10];
    float* out = (float*)d_out;

    char* w = (char*)d_ws;
    auto alloc = [&](size_t bytes) -> char* {
        char* p = w;
        w += (bytes + 255) & ~(size_t)255;
        return p;
    };
    int*   off      = (int*)alloc((size_t)(N_NODES + 1) * 4);
    int*   csr_src  = (int*)alloc((size_t)N_EDGES * 4);
    unsigned long long* pairs = (unsigned long long*)alloc((size_t)N_EDGES * 8);
    int*   bucketTotal  = (int*)alloc((size_t)(NBKT + 1) * 4);
    int*   bucketBase   = (int*)alloc((size_t)(NBKT + 1) * 4);
    int*   bucketCursor = (int*)alloc((size_t)(NBKT + 1) * 4);
    unsigned char*  h1f8 = (unsigned char*)alloc((size_t)N_NODES * HD1);
    unsigned short* el1b = (unsigned short*)alloc((size_t)N_NODES * HEADS * 2);
    float* er1v    = (float*)alloc((size_t)N_NODES * HEADS * 4);
    unsigned short* x2b = (unsigned short*)alloc((size_t)N_NODES * HD1 * 2);
    unsigned short* h2b = (unsigned short*)alloc((size_t)N_NODES * NC * 2);
    float* el2v    = (float*)alloc((size_t)N_NODES * 4);
    float* er2v    = (float*)alloc((size_t)N_NODES * 4);
    short* WTH     = (short*)alloc((size_t)F_IN * HD1 * 2);

    // CSR build (bucketed two-pass, no random global scatter)
    hipMemsetAsync(bucketTotal, 0, (size_t)(NBKT + 1) * 4, stream);
    k_p1hist<<<P1_BLOCKS, 256, 0, stream>>>(dst, bucketTotal);
    k_p1scan<<<1, 256, 0, stream>>>(bucketTotal, bucketBase, bucketCursor, off);
    k_p1bin<<<P1_BLOCKS, 256, 0, stream>>>(src, dst, bucketCursor, pairs);
    k_p2place<<<NBKT, 256, 0, stream>>>(pairs, bucketBase, off, csr_src);

    // Layer 1 compute
    k_splitW<<<(F_IN * HD1 + 255) / 256, 256, 0, stream>>>(W1, WTH);
    k_gemm1m<<<(N_NODES + 127) / 128, 256, 0, stream>>>(feat, WTH, h1f8);
    k_attn1<<<(N_NODES * HEADS + 255) / 256, 256, 0, stream>>>(h1f8, al1, ar1, el1b, er1v);

    // Layer-1 aggregation
    k_agg1<<<(N_NODES + 3) / 4, 256, 0, stream>>>(off, csr_src, el1b, er1v, h1f8, b1, x2b);

    // Layer 2
    k_gemm2<<<1024, 256, 0, stream>>>(x2b, W2, al2, ar2, h2b, el2v, er2v);
    k_agg2<<<(N_NODES + 15) / 16, 256, 0, stream>>>(off, csr_src, el2v, er2v, h2b, b2, out);
}

// Round 16
// 222.799 us; speedup vs baseline: 1.1061x; 1.0174x over previous
//
#include <hip/hip_runtime.h>

#define N_NODES 100000
#define N_EDGES 1600000
#define F_IN 256
#define HD1 128   // HEADS*HID
#define HEADS 8
#define HID 16
#define NC 16
#define NEG_SLOPE 0.2f
#define LOG2E 1.44269504f

// ---- bucketed CSR build params ----
#define BKT_NODES 512
#define NBKT ((N_NODES + BKT_NODES - 1) / BKT_NODES)   // 196
#define P1_EPB 8192
#define P1_BLOCKS ((N_EDGES + P1_EPB - 1) / P1_EPB)    // 196

__device__ __forceinline__ float leaky(float x){ return x > 0.f ? x : NEG_SLOPE * x; }
__device__ __forceinline__ unsigned short f2bf(float f){
    unsigned u = __float_as_uint(f);
    u += 0x7fff + ((u >> 16) & 1);       // round-to-nearest-even
    return (unsigned short)(u >> 16);
}
__device__ __forceinline__ float bf2f(unsigned short s){
    return __uint_as_float((unsigned)s << 16);
}
__device__ __forceinline__ unsigned char f2fp8(float v){
    return (unsigned char)(__builtin_amdgcn_cvt_pk_fp8_f32(v, v, 0, false) & 0xff);
}
// hardware packed fp32->bf16 (RNE), 2 floats -> 1 dword
__device__ __forceinline__ unsigned cvtpk_bf16(float lo, float hi){
    unsigned r;
    asm("v_cvt_pk_bf16_f32 %0, %1, %2" : "=v"(r) : "v"(lo), "v"(hi));
    return r;
}

typedef __bf16 bf16x8 __attribute__((ext_vector_type(8)));
typedef short short8 __attribute__((ext_vector_type(8)));
typedef float f32x4 __attribute__((ext_vector_type(4)));
typedef float f32x2 __attribute__((ext_vector_type(2)));

// ---------------- CSR build: bucketed, no random global scatter ----------------

__global__ void __launch_bounds__(256) k_p1hist(const int* __restrict__ dst, int* __restrict__ bucketTotal){
    __shared__ int h[NBKT];
    int t = threadIdx.x;
    for (int i = t; i < NBKT; i += 256) h[i] = 0;
    __syncthreads();
    int base = blockIdx.x * P1_EPB;
    int m = min(P1_EPB, N_EDGES - base);
    for (int i = t; i < m; i += 256) atomicAdd(&h[(unsigned)dst[base + i] >> 9], 1);
    __syncthreads();
    for (int i = t; i < NBKT; i += 256) if (h[i]) atomicAdd(&bucketTotal[i], h[i]);
}

__global__ void __launch_bounds__(256) k_p1scan(const int* __restrict__ bucketTotal,
                                                int* __restrict__ bucketBase, int* __restrict__ bucketCursor,
                                                int* __restrict__ off){
    __shared__ int sc[256];
    int t = threadIdx.x;
    int v = (t < NBKT) ? bucketTotal[t] : 0;
    sc[t] = v; __syncthreads();
    for (int o = 1; o < 256; o <<= 1){
        int a = (t >= o) ? sc[t - o] : 0;
        __syncthreads();
        sc[t] += a;
        __syncthreads();
    }
    if (t < NBKT){
        int b = sc[t] - v;         // exclusive
        bucketBase[t] = b;
        bucketCursor[t] = b;
    }
    if (t == 0){ bucketBase[NBKT] = N_EDGES; off[N_NODES] = N_EDGES; }
}

__global__ void __launch_bounds__(256) k_p1bin(const int* __restrict__ src, const int* __restrict__ dst,
                                               int* __restrict__ bucketCursor,
                                               unsigned long long* __restrict__ pairs){
    __shared__ unsigned long long pl[P1_EPB];   // 64 KB
    __shared__ int h[NBKT];                     // hist -> running cursor
    __shared__ int dl[NBKT];                    // global-base minus local-base
    __shared__ int sc[256];
    int t = threadIdx.x;
    for (int i = t; i < NBKT; i += 256) h[i] = 0;
    __syncthreads();
    int base = blockIdx.x * P1_EPB;
    int m = min(P1_EPB, N_EDGES - base);
    for (int i = t; i < m; i += 256) atomicAdd(&h[(unsigned)dst[base + i] >> 9], 1);
    __syncthreads();
    int v = (t < NBKT) ? h[t] : 0;
    sc[t] = v; __syncthreads();
    for (int o = 1; o < 256; o <<= 1){
        int a = (t >= o) ? sc[t - o] : 0;
        __syncthreads();
        sc[t] += a;
        __syncthreads();
    }
    if (t < NBKT){
        int ex = sc[t] - v;                        // local exclusive base
        int gb = v ? atomicAdd(&bucketCursor[t], v) : 0;
        dl[t] = gb - ex;
        h[t] = ex;                                 // reuse as running local cursor
    }
    __syncthreads();
    for (int i = t; i < m; i += 256){
        int d = dst[base + i], s = src[base + i];
        int b = (unsigned)d >> 9;
        int p = atomicAdd(&h[b], 1);
        pl[p] = ((unsigned long long)(unsigned)d << 32) | (unsigned)s;
    }
    __syncthreads();
    for (int i = t; i < m; i += 256){
        unsigned long long pr = pl[i];
        int b = (unsigned)(pr >> 32) >> 9;
        pairs[i + dl[b]] = pr;                     // sequential-run writes
    }
}

__global__ void __launch_bounds__(256) k_p2place(const unsigned long long* __restrict__ pairs,
                                                 const int* __restrict__ bucketBase,
                                                 int* __restrict__ off, int* __restrict__ csr_src){
    __shared__ int degc[BKT_NODES];
    __shared__ int sc2[BKT_NODES];
    int t = threadIdx.x;
    int b = blockIdx.x;
    int node0 = b * BKT_NODES;
    int nmax = min(BKT_NODES, N_NODES - node0);
    int p0 = bucketBase[b], p1 = bucketBase[b + 1];
    int m = p1 - p0;
    for (int i = t; i < BKT_NODES; i += 256) degc[i] = 0;
    __syncthreads();
    for (int i = t; i < m; i += 256){
        int d = (int)(pairs[p0 + i] >> 32) - node0;
        atomicAdd(&degc[d], 1);
    }
    __syncthreads();
    for (int i = t; i < BKT_NODES; i += 256) sc2[i] = degc[i];
    __syncthreads();
    // Hillis-Steele inclusive scan over 512 with 256 threads
    for (int o = 1; o < BKT_NODES; o <<= 1){
        int i0 = t, i1 = t + 256;
        int a0 = (i0 >= o) ? sc2[i0 - o] : 0;
        int a1 = (i1 >= o) ? sc2[i1 - o] : 0;
        __syncthreads();
        sc2[i0] += a0; sc2[i1] += a1;
        __syncthreads();
    }
    for (int i = t; i < BKT_NODES; i += 256){
        int cur = p0 + sc2[i] - degc[i];           // global exclusive offset
        if (i < nmax) off[node0 + i] = cur;
        degc[i] = cur;                              // becomes global cursor
    }
    __syncthreads();
    for (int i = t; i < m; i += 256){
        unsigned long long pr = pairs[p0 + i];
        int d = (int)(pr >> 32) - node0;
        int pos = atomicAdd(&degc[d], 1);
        csr_src[pos] = (int)(unsigned)pr;          // random only within 32KB window
    }
}

// ---------------- W1 -> bf16, transpose + XOR-swizzle ----------------

__global__ void __launch_bounds__(256) k_splitW(const float* __restrict__ W1,
                                                short* __restrict__ WTH){
    int i = blockIdx.x * 256 + threadIdx.x;   // 32768 elems
    if (i >= F_IN * HD1) return;
    int k = i >> 7, n = i & 127;
    int idx = n * 256 + (k ^ ((n & 7) << 3));
    WTH[idx] = (short)f2bf(W1[i]);
}

// ---------------- GEMM1 (MFMA bf16): h1f8 = fp8(feat @ W1) ----------------
// Single pass over all 128 cols, 512-thread blocks (8 waves): 64KB W-LDS,
// 2 blocks/CU -> 16 waves/CU of outstanding feat loads (latency-bound regime).

__device__ __forceinline__ short8 pack8(float4 f0, float4 f1){
    uint4 p;
    p.x = cvtpk_bf16(f0.x, f0.y);
    p.y = cvtpk_bf16(f0.z, f0.w);
    p.z = cvtpk_bf16(f1.x, f1.y);
    p.w = cvtpk_bf16(f1.z, f1.w);
    return __builtin_bit_cast(short8, p);
}

__global__ void __launch_bounds__(512, 4) k_gemm1m(const float* __restrict__ feat,
                                                   const short* __restrict__ WTH,
                                                   unsigned char* __restrict__ h1f8){
    __shared__ short sWH[F_IN * HD1];   // 64 KB
    int t = threadIdx.x;
    {
        const short8* gh = (const short8*)WTH;
        short8* sh = (short8*)sWH;
        for (int i = t; i < 4096; i += 512) sh[i] = gh[i];
    }
    __syncthreads();

    int wid = t >> 6, lane = t & 63;
    int m16 = lane & 15, kg = lane >> 4;
    int rowb = blockIdx.x * 256 + wid * 32;

    f32x4 acc[2][8];
    #pragma unroll
    for (int a = 0; a < 2; a++)
        #pragma unroll
        for (int b = 0; b < 8; b++)
            acc[a][b] = (f32x4){0.f, 0.f, 0.f, 0.f};

    int r0 = rowb + m16;       if (r0 > N_NODES - 1) r0 = N_NODES - 1;
    int r1 = rowb + 16 + m16;  if (r1 > N_NODES - 1) r1 = N_NODES - 1;
    const float* fp0 = feat + (size_t)r0 * F_IN;
    const float* fp1 = feat + (size_t)r1 * F_IN;

    #pragma unroll
    for (int ks = 0; ks < 8; ks++){
        int kbase = ks * 32 + kg * 8;
        short8 a0, a1;
        {
            const float4* p = (const float4*)(fp0 + kbase);
            a0 = pack8(p[0], p[1]);
        }
        {
            const float4* p = (const float4*)(fp1 + kbase);
            a1 = pack8(p[0], p[1]);
        }
        bf16x8 AH0 = __builtin_bit_cast(bf16x8, a0);
        bf16x8 AH1 = __builtin_bit_cast(bf16x8, a1);
        #pragma unroll
        for (int c = 0; c < 8; c++){
            int n = (c << 4) + m16;
            int kk = kbase ^ ((n & 7) << 3);
            bf16x8 bh = __builtin_bit_cast(bf16x8, *(const short8*)(sWH + n * 256 + kk));
            acc[0][c] = __builtin_amdgcn_mfma_f32_16x16x32_bf16(AH0, bh, acc[0][c], 0, 0, 0);
            acc[1][c] = __builtin_amdgcn_mfma_f32_16x16x32_bf16(AH1, bh, acc[1][c], 0, 0, 0);
        }
    }

    #pragma unroll
    for (int rf = 0; rf < 2; rf++){
        #pragma unroll
        for (int c = 0; c < 8; c++){
            #pragma unroll
            for (int r = 0; r < 4; r++){
                int row = rowb + rf * 16 + kg * 4 + r;
                if (row < N_NODES){
                    int col = c * 16 + m16;
                    h1f8[(size_t)row * HD1 + col] = f2fp8(acc[rf][c][r]);
                }
            }
        }
    }
}

// ---------------- el1/er1 from h1f8 (pre-scaled by log2e; el1 bf16, er1 fp32) ----------------

__global__ void __launch_bounds__(256) k_attn1(const unsigned char* __restrict__ h1f8,
                                               const float* __restrict__ al1, const float* __restrict__ ar1,
                                               unsigned short* __restrict__ el1b, float* __restrict__ er1){
    int i = blockIdx.x * 256 + threadIdx.x;
    if (i >= N_NODES * HEADS) return;
    int n = i >> 3, h = i & 7;
    const unsigned* hp = (const unsigned*)(h1f8 + (size_t)n * HD1 + h * HID);
    float pe = 0.f, pr = 0.f;
    #pragma unroll
    for (int j = 0; j < 4; j++){
        unsigned u = hp[j];
        float x0 = __builtin_amdgcn_cvt_f32_fp8(u, 0);
        float x1 = __builtin_amdgcn_cvt_f32_fp8(u, 1);
        float x2 = __builtin_amdgcn_cvt_f32_fp8(u, 2);
        float x3 = __builtin_amdgcn_cvt_f32_fp8(u, 3);
        const float4 a = ((const float4*)(al1 + h * HID))[j];
        const float4 r = ((const float4*)(ar1 + h * HID))[j];
        pe += x0 * a.x + x1 * a.y + x2 * a.z + x3 * a.w;
        pr += x0 * r.x + x1 * r.y + x2 * r.z + x3 * r.w;
    }
    el1b[i] = f2bf(pe * LOG2E);      // leaky(k x)=k leaky(x): exp(leaky(e)) = exp2(leaky(e*log2e))
    er1[i] = pr * LOG2E;
}

// ---------------- Layer-1 aggregation: 1 wave/node, 16 lanes/edge, 4 edges/iter ----------------

__global__ void __launch_bounds__(256) k_agg1(const int* __restrict__ off, const int* __restrict__ csr_src,
                                              const unsigned short* __restrict__ el1b,
                                              const float* __restrict__ er1,
                                              const unsigned char* __restrict__ h1f8,
                                              const float* __restrict__ b1,
                                              unsigned short* __restrict__ x2b){
    int wid = threadIdx.x >> 6, lane = threadIdx.x & 63;
    int n = blockIdx.x * 4 + wid;
    if (n >= N_NODES) return;
    int jb = off[n], je = off[n + 1];
    int sub = lane >> 4;       // edge slot within quad (0..3)
    int q = lane & 15;         // column group: cols q*8 .. q*8+7
    int hh = q >> 1;           // head (2 lanes per head)
    float ern = er1[n * HEADS + hh];
    float a0=0.f,a1=0.f,a2=0.f,a3=0.f,a4=0.f,a5=0.f,a6=0.f,a7=0.f,wsum=0.f;

    #pragma unroll 4
    for (int j = jb; j < je; j += 4){
        int jj = j + sub;
        int jc = (jj < je) ? jj : je - 1;
        int s = csr_src[jc];
        float el = bf2f(el1b[s * HEADS + hh]);
        float wv = (jj < je) ? __builtin_amdgcn_exp2f(leaky(el + ern)) : 0.f;
        wsum += wv;
        uint2 u = *(const uint2*)(h1f8 + (((size_t)s) << 7) + (q << 3));
        f32x2 p0 = __builtin_amdgcn_cvt_pk_f32_fp8(u.x, 0);
        f32x2 p1 = __builtin_amdgcn_cvt_pk_f32_fp8(u.x, 1);
        f32x2 p2 = __builtin_amdgcn_cvt_pk_f32_fp8(u.y, 0);
        f32x2 p3 = __builtin_amdgcn_cvt_pk_f32_fp8(u.y, 1);
        a0 += wv * p0.x; a1 += wv * p0.y;
        a2 += wv * p1.x; a3 += wv * p1.y;
        a4 += wv * p2.x; a5 += wv * p2.y;
        a6 += wv * p3.x; a7 += wv * p3.y;
    }

    // reduce across the 4 edge-slots (lanes differing in bits 4,5)
    a0 += __shfl_xor(a0, 16); a0 += __shfl_xor(a0, 32);
    a1 += __shfl_xor(a1, 16); a1 += __shfl_xor(a1, 32);
    a2 += __shfl_xor(a2, 16); a2 += __shfl_xor(a2, 32);
    a3 += __shfl_xor(a3, 16); a3 += __shfl_xor(a3, 32);
    a4 += __shfl_xor(a4, 16); a4 += __shfl_xor(a4, 32);
    a5 += __shfl_xor(a5, 16); a5 += __shfl_xor(a5, 32);
    a6 += __shfl_xor(a6, 16); a6 += __shfl_xor(a6, 32);
    a7 += __shfl_xor(a7, 16); a7 += __shfl_xor(a7, 32);
    wsum += __shfl_xor(wsum, 16); wsum += __shfl_xor(wsum, 32);

    if (sub == 0){
        float inv = (je > jb) ? 1.f / wsum : 0.f;
        float o0 = a0*inv, o1 = a1*inv, o2 = a2*inv, o3 = a3*inv;
        float o4 = a4*inv, o5 = a5*inv, o6 = a6*inv, o7 = a7*inv;
        float4 bv0 = *(const float4*)(b1 + (q << 3));
        float4 bv1 = *(const float4*)(b1 + (q << 3) + 4);
        o0 += bv0.x; o1 += bv0.y; o2 += bv0.z; o3 += bv0.w;
        o4 += bv1.x; o5 += bv1.y; o6 += bv1.z; o7 += bv1.w;
        o0 = o0 > 0.f ? o0 : __expf(o0) - 1.f;
        o1 = o1 > 0.f ? o1 : __expf(o1) - 1.f;
        o2 = o2 > 0.f ? o2 : __expf(o2) - 1.f;
        o3 = o3 > 0.f ? o3 : __expf(o3) - 1.f;
        o4 = o4 > 0.f ? o4 : __expf(o4) - 1.f;
        o5 = o5 > 0.f ? o5 : __expf(o5) - 1.f;
        o6 = o6 > 0.f ? o6 : __expf(o6) - 1.f;
        o7 = o7 > 0.f ? o7 : __expf(o7) - 1.f;
        uint4 ov;
        ov.x = cvtpk_bf16(o0, o1);
        ov.y = cvtpk_bf16(o2, o3);
        ov.z = cvtpk_bf16(o4, o5);
        ov.w = cvtpk_bf16(o6, o7);
        *(uint4*)(x2b + (size_t)n * HD1 + (q << 3)) = ov;
    }
}

// ---------------- GEMM2: h2e rows = [16 x bf16 h2 | fp32 el2 | pad] (64B) ----------------

__global__ void __launch_bounds__(256) k_gemm2(const unsigned short* __restrict__ x2b, const float* __restrict__ W2,
                                               const float* __restrict__ al2, const float* __restrict__ ar2,
                                               unsigned short* __restrict__ h2e, float* __restrict__ er2){
    __shared__ float sW[HD1 * NC];   // 8 KB
    __shared__ float sX[16 * HD1];   // 8 KB
    int t = threadIdx.x;
    for (int i = t; i < (HD1 * NC) / 4; i += 256)
        ((float4*)sW)[i] = ((const float4*)W2)[i];
    int r = t >> 4, c = t & 15;
    float a2 = al2[c], r2 = ar2[c];
    for (int g = blockIdx.x; g * 16 < N_NODES; g += gridDim.x){
        int rowb = g * 16;
        __syncthreads();
        {
            ushort4 v = ((const ushort4*)(x2b + (size_t)rowb * HD1))[t * 2];
            ushort4 v2 = ((const ushort4*)(x2b + (size_t)rowb * HD1))[t * 2 + 1];
            float4 f0 = { bf2f(v.x), bf2f(v.y), bf2f(v.z), bf2f(v.w) };
            float4 f1 = { bf2f(v2.x), bf2f(v2.y), bf2f(v2.z), bf2f(v2.w) };
            ((float4*)sX)[t * 2] = f0;
            ((float4*)sX)[t * 2 + 1] = f1;
        }
        __syncthreads();
        float acc = 0.f;
        #pragma unroll 8
        for (int k = 0; k < HD1; k++)
            acc += sX[r * HD1 + k] * sW[k * NC + c];
        int row = rowb + r;
        h2e[(size_t)row * 32 + c] = f2bf(acc);
        float pe = acc * a2, pr = acc * r2;
        #pragma unroll
        for (int d = 1; d < 16; d <<= 1){ pe += __shfl_xor(pe, d); pr += __shfl_xor(pr, d); }
        if (c == 0){
            *(float*)(h2e + (size_t)row * 32 + 16) = pe * LOG2E;
            er2[row] = pr * LOG2E;
        }
    }
}

// ---------------- Layer-2 aggregation + bias + log_softmax ----------------

__global__ void __launch_bounds__(256) k_agg2(const int* __restrict__ off, const int* __restrict__ csr_src,
                                              const float* __restrict__ er2,
                                              const unsigned short* __restrict__ h2e, const float* __restrict__ b2,
                                              float* __restrict__ out){
    int t = threadIdx.x;
    int sub = t >> 4;          // 16 nodes per block
    int c = t & 15;
    int n = blockIdx.x * 16 + sub;
    if (n >= N_NODES) return;
    int jb = off[n], je = off[n + 1];
    float er = er2[n];
    float accA = 0.f, accB = 0.f, wsA = 0.f, wsB = 0.f;
    int j = jb;
    for (; j + 1 < je; j += 2){
        int s0 = csr_src[j];
        int s1 = csr_src[j + 1];
        const unsigned short* r0 = h2e + (size_t)s0 * 32;
        const unsigned short* r1 = h2e + (size_t)s1 * 32;
        float el0 = *(const float*)(r0 + 16);
        float el1 = *(const float*)(r1 + 16);
        float w0 = __builtin_amdgcn_exp2f(leaky(el0 + er));
        float w1 = __builtin_amdgcn_exp2f(leaky(el1 + er));
        float v0 = bf2f(r0[c]);
        float v1 = bf2f(r1[c]);
        wsA += w0; accA += w0 * v0;
        wsB += w1; accB += w1 * v1;
    }
    if (j < je){
        int s0 = csr_src[j];
        const unsigned short* r0 = h2e + (size_t)s0 * 32;
        float el0 = *(const float*)(r0 + 16);
        float w0 = __builtin_amdgcn_exp2f(leaky(el0 + er));
        wsA += w0; accA += w0 * bf2f(r0[c]);
    }
    float acc = accA + accB, wsum = wsA + wsB;
    float o = (je > jb) ? acc / wsum : 0.f;
    o += b2[c];
    // log_softmax over the 16 classes (16-lane group)
    float m = o;
    #pragma unroll
    for (int d = 1; d < 16; d <<= 1) m = fmaxf(m, __shfl_xor(m, d));
    float ex = __expf(o - m);
    #pragma unroll
    for (int d = 1; d < 16; d <<= 1) ex += __shfl_xor(ex, d);
    out[(size_t)n * NC + c] = o - m - __logf(ex);
}

// ---------------- launch ----------------

extern "C" void kernel_launch(void* const* d_in, const int* in_sizes, int n_in,
                              void* d_out, int out_size, void* d_ws, size_t ws_size,
                              hipStream_t stream){
    const float* feat = (const float*)d_in[0];
    const int*   src  = (const int*)d_in[1];
    const int*   dst  = (const int*)d_in[2];
    const float* W1   = (const float*)d_in[3];
    const float* al1  = (const float*)d_in[4];
    const float* ar1  = (const float*)d_in[5];
    const float* b1   = (const float*)d_in[6];
    const float* W2   = (const float*)d_in[7];
    const float* al2  = (const float*)d_in[8];
    const float* ar2  = (const float*)d_in[9];
    const float* b2   = (const float*)d_in[10];
    float* out = (float*)d_out;

    char* w = (char*)d_ws;
    auto alloc = [&](size_t bytes) -> char* {
        char* p = w;
        w += (bytes + 255) & ~(size_t)255;
        return p;
    };
    int*   off      = (int*)alloc((size_t)(N_NODES + 1) * 4);
    int*   csr_src  = (int*)alloc((size_t)N_EDGES * 4);
    unsigned long long* pairs = (unsigned long long*)alloc((size_t)N_EDGES * 8);
    int*   bucketTotal  = (int*)alloc((size_t)(NBKT + 1) * 4);
    int*   bucketBase   = (int*)alloc((size_t)(NBKT + 1) * 4);
    int*   bucketCursor = (int*)alloc((size_t)(NBKT + 1) * 4);
    unsigned char*  h1f8 = (unsigned char*)alloc((size_t)N_NODES * HD1);
    unsigned short* el1b = (unsigned short*)alloc((size_t)N_NODES * HEADS * 2);
    float* er1v    = (float*)alloc((size_t)N_NODES * HEADS * 4);
    unsigned short* x2b = (unsigned short*)alloc((size_t)N_NODES * HD1 * 2);
    unsigned short* h2e = (unsigned short*)alloc((size_t)N_NODES * 64);
    float* er2v    = (float*)alloc((size_t)N_NODES * 4);
    short* WTH     = (short*)alloc((size_t)F_IN * HD1 * 2);

    // CSR build (bucketed two-pass, no random global scatter)
    hipMemsetAsync(bucketTotal, 0, (size_t)(NBKT + 1) * 4, stream);
    k_p1hist<<<P1_BLOCKS, 256, 0, stream>>>(dst, bucketTotal);
    k_p1scan<<<1, 256, 0, stream>>>(bucketTotal, bucketBase, bucketCursor, off);
    k_p1bin<<<P1_BLOCKS, 256, 0, stream>>>(src, dst, bucketCursor, pairs);
    k_p2place<<<NBKT, 256, 0, stream>>>(pairs, bucketBase, off, csr_src);

    // Layer 1 compute
    k_splitW<<<(F_IN * HD1 + 255) / 256, 256, 0, stream>>>(W1, WTH);
    k_gemm1m<<<(N_NODES + 255) / 256, 512, 0, stream>>>(feat, WTH, h1f8);
    k_attn1<<<(N_NODES * HEADS + 255) / 256, 256, 0, stream>>>(h1f8, al1, ar1, el1b, er1v);

    // Layer-1 aggregation
    k_agg1<<<(N_NODES + 3) / 4, 256, 0, stream>>>(off, csr_src, el1b, er1v, h1f8, b1, x2b);

    // Layer 2
    k_gemm2<<<1024, 256, 0, stream>>>(x2b, W2, al2, ar2, h2e, er2v);
    k_agg2<<<(N_NODES + 15) / 16, 256, 0, stream>>>(off, csr_src, er2v, h2e, b2, out);
}

// Round 17
// 204.545 us; speedup vs baseline: 1.2048x; 1.0892x over previous
//
#include <hip/hip_runtime.h>

#define N_NODES 100000
#define N_EDGES 1600000
#define F_IN 256
#define HD1 128   // HEADS*HID
#define HEADS 8
#define HID 16
#define NC 16
#define NEG_SLOPE 0.2f
#define LOG2E 1.44269504f

// ---- bucketed CSR build params ----
#define BKT_NODES 512
#define NBKT ((N_NODES + BKT_NODES - 1) / BKT_NODES)   // 196
#define P1_EPB 8192
#define P1_BLOCKS ((N_EDGES + P1_EPB - 1) / P1_EPB)    // 196
#define SPLITW_BLOCKS ((F_IN * HD1) / 256)             // 128

__device__ __forceinline__ float leaky(float x){ return x > 0.f ? x : NEG_SLOPE * x; }
__device__ __forceinline__ unsigned short f2bf(float f){
    unsigned u = __float_as_uint(f);
    u += 0x7fff + ((u >> 16) & 1);       // round-to-nearest-even
    return (unsigned short)(u >> 16);
}
__device__ __forceinline__ float bf2f(unsigned short s){
    return __uint_as_float((unsigned)s << 16);
}
__device__ __forceinline__ unsigned char f2fp8(float v){
    return (unsigned char)(__builtin_amdgcn_cvt_pk_fp8_f32(v, v, 0, false) & 0xff);
}
// hardware packed fp32->bf16 (RNE), 2 floats -> 1 dword
__device__ __forceinline__ unsigned cvtpk_bf16(float lo, float hi){
    unsigned r;
    asm("v_cvt_pk_bf16_f32 %0, %1, %2" : "=v"(r) : "v"(lo), "v"(hi));
    return r;
}

typedef __bf16 bf16x8 __attribute__((ext_vector_type(8)));
typedef short short8 __attribute__((ext_vector_type(8)));
typedef float f32x4 __attribute__((ext_vector_type(4)));
typedef float f32x2 __attribute__((ext_vector_type(2)));

// ---------------- CSR phase 1a: per-block hist (no atomics) + fused W1 split ----------------

__global__ void __launch_bounds__(256) k_p1hist(const int* __restrict__ dst, int* __restrict__ bucketPart,
                                                const float* __restrict__ W1, short* __restrict__ WTH){
    int t = threadIdx.x;
    int bid = blockIdx.x;
    if (bid >= P1_BLOCKS){
        // fused splitW: W1 -> bf16, transpose + XOR-swizzle
        int i = (bid - P1_BLOCKS) * 256 + t;
        int k = i >> 7, n = i & 127;
        int idx = n * 256 + (k ^ ((n & 7) << 3));
        WTH[idx] = (short)f2bf(W1[i]);
        return;
    }
    __shared__ int h[NBKT];
    for (int i = t; i < NBKT; i += 256) h[i] = 0;
    __syncthreads();
    int base = bid * P1_EPB;
    int m = min(P1_EPB, N_EDGES - base);
    for (int i = t; i < m; i += 256) atomicAdd(&h[(unsigned)dst[base + i] >> 9], 1);
    __syncthreads();
    for (int i = t; i < NBKT; i += 256) bucketPart[bid * NBKT + i] = h[i];
}

__global__ void __launch_bounds__(256) k_p1scan(const int* __restrict__ bucketPart,
                                                int* __restrict__ bucketBase, int* __restrict__ bucketCursor,
                                                int* __restrict__ off){
    __shared__ int sc[256];
    int t = threadIdx.x;
    int v = 0;
    if (t < NBKT)
        for (int b = 0; b < P1_BLOCKS; b++) v += bucketPart[b * NBKT + t];
    sc[t] = v; __syncthreads();
    for (int o = 1; o < 256; o <<= 1){
        int a = (t >= o) ? sc[t - o] : 0;
        __syncthreads();
        sc[t] += a;
        __syncthreads();
    }
    if (t < NBKT){
        int b = sc[t] - v;         // exclusive
        bucketBase[t] = b;
        bucketCursor[t] = b;
    }
    if (t == 0){ bucketBase[NBKT] = N_EDGES; off[N_NODES] = N_EDGES; }
}

__global__ void __launch_bounds__(256) k_p1bin(const int* __restrict__ src, const int* __restrict__ dst,
                                               const int* __restrict__ bucketPart,
                                               int* __restrict__ bucketCursor,
                                               unsigned long long* __restrict__ pairs){
    __shared__ unsigned long long pl[P1_EPB];   // 64 KB
    __shared__ int h[NBKT];                     // local hist -> running cursor
    __shared__ int dl[NBKT];                    // global-base minus local-base
    __shared__ int sc[256];
    int t = threadIdx.x;
    int bid = blockIdx.x;
    // local hist comes precomputed from p1hist
    int v = (t < NBKT) ? bucketPart[bid * NBKT + t] : 0;
    sc[t] = v; __syncthreads();
    for (int o = 1; o < 256; o <<= 1){
        int a = (t >= o) ? sc[t - o] : 0;
        __syncthreads();
        sc[t] += a;
        __syncthreads();
    }
    if (t < NBKT){
        int ex = sc[t] - v;                        // local exclusive base
        int gb = v ? atomicAdd(&bucketCursor[t], v) : 0;
        dl[t] = gb - ex;
        h[t] = ex;                                 // running local cursor
    }
    __syncthreads();
    int base = bid * P1_EPB;
    int m = min(P1_EPB, N_EDGES - base);
    for (int i = t; i < m; i += 256){
        int d = dst[base + i], s = src[base + i];
        int b = (unsigned)d >> 9;
        int p = atomicAdd(&h[b], 1);
        pl[p] = ((unsigned long long)(unsigned)d << 32) | (unsigned)s;
    }
    __syncthreads();
    for (int i = t; i < m; i += 256){
        unsigned long long pr = pl[i];
        int b = (unsigned)(pr >> 32) >> 9;
        pairs[i + dl[b]] = pr;                     // sequential-run writes
    }
}

__global__ void __launch_bounds__(256) k_p2place(const unsigned long long* __restrict__ pairs,
                                                 const int* __restrict__ bucketBase,
                                                 int* __restrict__ off, int* __restrict__ csr_src){
    __shared__ int degc[BKT_NODES];
    __shared__ int sc2[BKT_NODES];
    int t = threadIdx.x;
    int b = blockIdx.x;
    int node0 = b * BKT_NODES;
    int nmax = min(BKT_NODES, N_NODES - node0);
    int p0 = bucketBase[b], p1 = bucketBase[b + 1];
    int m = p1 - p0;
    for (int i = t; i < BKT_NODES; i += 256) degc[i] = 0;
    __syncthreads();
    for (int i = t; i < m; i += 256){
        int d = (int)(pairs[p0 + i] >> 32) - node0;
        atomicAdd(&degc[d], 1);
    }
    __syncthreads();
    for (int i = t; i < BKT_NODES; i += 256) sc2[i] = degc[i];
    __syncthreads();
    // Hillis-Steele inclusive scan over 512 with 256 threads
    for (int o = 1; o < BKT_NODES; o <<= 1){
        int i0 = t, i1 = t + 256;
        int a0 = (i0 >= o) ? sc2[i0 - o] : 0;
        int a1 = (i1 >= o) ? sc2[i1 - o] : 0;
        __syncthreads();
        sc2[i0] += a0; sc2[i1] += a1;
        __syncthreads();
    }
    for (int i = t; i < BKT_NODES; i += 256){
        int cur = p0 + sc2[i] - degc[i];           // global exclusive offset
        if (i < nmax) off[node0 + i] = cur;
        degc[i] = cur;                              // becomes global cursor
    }
    __syncthreads();
    for (int i = t; i < m; i += 256){
        unsigned long long pr = pairs[p0 + i];
        int d = (int)(pr >> 32) - node0;
        int pos = atomicAdd(&degc[d], 1);
        csr_src[pos] = (int)(unsigned)pr;          // random only within 32KB window
    }
}

// ---------------- GEMM1 (MFMA bf16): h1f8 = fp8(feat @ W1) ----------------
// Single pass over all 128 cols, 512-thread blocks: 64KB W-LDS, feat read once.
// setprio(1) around MFMA cluster (barrier-free desynced waves -> T5 regime).

__device__ __forceinline__ short8 pack8(float4 f0, float4 f1){
    uint4 p;
    p.x = cvtpk_bf16(f0.x, f0.y);
    p.y = cvtpk_bf16(f0.z, f0.w);
    p.z = cvtpk_bf16(f1.x, f1.y);
    p.w = cvtpk_bf16(f1.z, f1.w);
    return __builtin_bit_cast(short8, p);
}

__global__ void __launch_bounds__(512, 4) k_gemm1m(const float* __restrict__ feat,
                                                   const short* __restrict__ WTH,
                                                   unsigned char* __restrict__ h1f8){
    __shared__ short sWH[F_IN * HD1];   // 64 KB
    int t = threadIdx.x;
    {
        const short8* gh = (const short8*)WTH;
        short8* sh = (short8*)sWH;
        for (int i = t; i < 4096; i += 512) sh[i] = gh[i];
    }
    __syncthreads();

    int wid = t >> 6, lane = t & 63;
    int m16 = lane & 15, kg = lane >> 4;
    int rowb = blockIdx.x * 256 + wid * 32;

    f32x4 acc[2][8];
    #pragma unroll
    for (int a = 0; a < 2; a++)
        #pragma unroll
        for (int b = 0; b < 8; b++)
            acc[a][b] = (f32x4){0.f, 0.f, 0.f, 0.f};

    int r0 = rowb + m16;       if (r0 > N_NODES - 1) r0 = N_NODES - 1;
    int r1 = rowb + 16 + m16;  if (r1 > N_NODES - 1) r1 = N_NODES - 1;
    const float* fp0 = feat + (size_t)r0 * F_IN;
    const float* fp1 = feat + (size_t)r1 * F_IN;

    #pragma unroll
    for (int ks = 0; ks < 8; ks++){
        int kbase = ks * 32 + kg * 8;
        short8 a0, a1;
        {
            const float4* p = (const float4*)(fp0 + kbase);
            a0 = pack8(p[0], p[1]);
        }
        {
            const float4* p = (const float4*)(fp1 + kbase);
            a1 = pack8(p[0], p[1]);
        }
        bf16x8 AH0 = __builtin_bit_cast(bf16x8, a0);
        bf16x8 AH1 = __builtin_bit_cast(bf16x8, a1);
        __builtin_amdgcn_s_setprio(1);
        #pragma unroll
        for (int c = 0; c < 8; c++){
            int n = (c << 4) + m16;
            int kk = kbase ^ ((n & 7) << 3);
            bf16x8 bh = __builtin_bit_cast(bf16x8, *(const short8*)(sWH + n * 256 + kk));
            acc[0][c] = __builtin_amdgcn_mfma_f32_16x16x32_bf16(AH0, bh, acc[0][c], 0, 0, 0);
            acc[1][c] = __builtin_amdgcn_mfma_f32_16x16x32_bf16(AH1, bh, acc[1][c], 0, 0, 0);
        }
        __builtin_amdgcn_s_setprio(0);
    }

    #pragma unroll
    for (int rf = 0; rf < 2; rf++){
        #pragma unroll
        for (int c = 0; c < 8; c++){
            #pragma unroll
            for (int r = 0; r < 4; r++){
                int row = rowb + rf * 16 + kg * 4 + r;
                if (row < N_NODES){
                    int col = c * 16 + m16;
                    h1f8[(size_t)row * HD1 + col] = f2fp8(acc[rf][c][r]);
                }
            }
        }
    }
}

// ---------------- el1/er1 from h1f8 (pre-scaled by log2e; el1 bf16, er1 fp32) ----------------

__global__ void __launch_bounds__(256) k_attn1(const unsigned char* __restrict__ h1f8,
                                               const float* __restrict__ al1, const float* __restrict__ ar1,
                                               unsigned short* __restrict__ el1b, float* __restrict__ er1){
    int i = blockIdx.x * 256 + threadIdx.x;
    if (i >= N_NODES * HEADS) return;
    int n = i >> 3, h = i & 7;
    uint4 hv = *(const uint4*)(h1f8 + (size_t)n * HD1 + h * HID);
    unsigned uu[4] = {hv.x, hv.y, hv.z, hv.w};
    float pe = 0.f, pr = 0.f;
    #pragma unroll
    for (int j = 0; j < 4; j++){
        unsigned u = uu[j];
        float x0 = __builtin_amdgcn_cvt_f32_fp8(u, 0);
        float x1 = __builtin_amdgcn_cvt_f32_fp8(u, 1);
        float x2 = __builtin_amdgcn_cvt_f32_fp8(u, 2);
        float x3 = __builtin_amdgcn_cvt_f32_fp8(u, 3);
        const float4 a = ((const float4*)(al1 + h * HID))[j];
        const float4 r = ((const float4*)(ar1 + h * HID))[j];
        pe += x0 * a.x + x1 * a.y + x2 * a.z + x3 * a.w;
        pr += x0 * r.x + x1 * r.y + x2 * r.z + x3 * r.w;
    }
    el1b[i] = f2bf(pe * LOG2E);      // leaky(k x)=k leaky(x): exp(leaky(e)) = exp2(leaky(e*log2e))
    er1[i] = pr * LOG2E;
}

// ---------------- Layer-1 aggregation: 1 wave/node, 16 lanes/edge, 4 edges/iter ----------------

__global__ void __launch_bounds__(256) k_agg1(const int* __restrict__ off, const int* __restrict__ csr_src,
                                              const unsigned short* __restrict__ el1b,
                                              const float* __restrict__ er1,
                                              const unsigned char* __restrict__ h1f8,
                                              const float* __restrict__ b1,
                                              unsigned short* __restrict__ x2b){
    int wid = threadIdx.x >> 6, lane = threadIdx.x & 63;
    int n = blockIdx.x * 4 + wid;
    if (n >= N_NODES) return;
    int jb = off[n], je = off[n + 1];
    int sub = lane >> 4;       // edge slot within quad (0..3)
    int q = lane & 15;         // column group: cols q*8 .. q*8+7
    int hh = q >> 1;           // head (2 lanes per head)
    float ern = er1[n * HEADS + hh];
    float a0=0.f,a1=0.f,a2=0.f,a3=0.f,a4=0.f,a5=0.f,a6=0.f,a7=0.f,wsum=0.f;

    #pragma unroll 4
    for (int j = jb; j < je; j += 4){
        int jj = j + sub;
        int jc = (jj < je) ? jj : je - 1;
        int s = csr_src[jc];
        float el = bf2f(el1b[s * HEADS + hh]);
        float wv = (jj < je) ? __builtin_amdgcn_exp2f(leaky(el + ern)) : 0.f;
        wsum += wv;
        uint2 u = *(const uint2*)(h1f8 + (((size_t)s) << 7) + (q << 3));
        f32x2 p0 = __builtin_amdgcn_cvt_pk_f32_fp8(u.x, 0);
        f32x2 p1 = __builtin_amdgcn_cvt_pk_f32_fp8(u.x, 1);
        f32x2 p2 = __builtin_amdgcn_cvt_pk_f32_fp8(u.y, 0);
        f32x2 p3 = __builtin_amdgcn_cvt_pk_f32_fp8(u.y, 1);
        a0 += wv * p0.x; a1 += wv * p0.y;
        a2 += wv * p1.x; a3 += wv * p1.y;
        a4 += wv * p2.x; a5 += wv * p2.y;
        a6 += wv * p3.x; a7 += wv * p3.y;
    }

    // reduce across the 4 edge-slots (lanes differing in bits 4,5)
    a0 += __shfl_xor(a0, 16); a0 += __shfl_xor(a0, 32);
    a1 += __shfl_xor(a1, 16); a1 += __shfl_xor(a1, 32);
    a2 += __shfl_xor(a2, 16); a2 += __shfl_xor(a2, 32);
    a3 += __shfl_xor(a3, 16); a3 += __shfl_xor(a3, 32);
    a4 += __shfl_xor(a4, 16); a4 += __shfl_xor(a4, 32);
    a5 += __shfl_xor(a5, 16); a5 += __shfl_xor(a5, 32);
    a6 += __shfl_xor(a6, 16); a6 += __shfl_xor(a6, 32);
    a7 += __shfl_xor(a7, 16); a7 += __shfl_xor(a7, 32);
    wsum += __shfl_xor(wsum, 16); wsum += __shfl_xor(wsum, 32);

    if (sub == 0){
        float inv = (je > jb) ? 1.f / wsum : 0.f;
        float o0 = a0*inv, o1 = a1*inv, o2 = a2*inv, o3 = a3*inv;
        float o4 = a4*inv, o5 = a5*inv, o6 = a6*inv, o7 = a7*inv;
        float4 bv0 = *(const float4*)(b1 + (q << 3));
        float4 bv1 = *(const float4*)(b1 + (q << 3) + 4);
        o0 += bv0.x; o1 += bv0.y; o2 += bv0.z; o3 += bv0.w;
        o4 += bv1.x; o5 += bv1.y; o6 += bv1.z; o7 += bv1.w;
        o0 = o0 > 0.f ? o0 : __expf(o0) - 1.f;
        o1 = o1 > 0.f ? o1 : __expf(o1) - 1.f;
        o2 = o2 > 0.f ? o2 : __expf(o2) - 1.f;
        o3 = o3 > 0.f ? o3 : __expf(o3) - 1.f;
        o4 = o4 > 0.f ? o4 : __expf(o4) - 1.f;
        o5 = o5 > 0.f ? o5 : __expf(o5) - 1.f;
        o6 = o6 > 0.f ? o6 : __expf(o6) - 1.f;
        o7 = o7 > 0.f ? o7 : __expf(o7) - 1.f;
        uint4 ov;
        ov.x = cvtpk_bf16(o0, o1);
        ov.y = cvtpk_bf16(o2, o3);
        ov.z = cvtpk_bf16(o4, o5);
        ov.w = cvtpk_bf16(o6, o7);
        *(uint4*)(x2b + (size_t)n * HD1 + (q << 3)) = ov;
    }
}

// ---------------- GEMM2: h2e rows = [16 x bf16 h2 | fp32 el2 | pad] (64B) ----------------

__global__ void __launch_bounds__(256) k_gemm2(const unsigned short* __restrict__ x2b, const float* __restrict__ W2,
                                               const float* __restrict__ al2, const float* __restrict__ ar2,
                                               unsigned short* __restrict__ h2e, float* __restrict__ er2){
    __shared__ float sW[HD1 * NC];   // 8 KB
    __shared__ float sX[16 * HD1];   // 8 KB
    int t = threadIdx.x;
    for (int i = t; i < (HD1 * NC) / 4; i += 256)
        ((float4*)sW)[i] = ((const float4*)W2)[i];
    int r = t >> 4, c = t & 15;
    float a2 = al2[c], r2 = ar2[c];
    for (int g = blockIdx.x; g * 16 < N_NODES; g += gridDim.x){
        int rowb = g * 16;
        __syncthreads();
        {
            ushort4 v = ((const ushort4*)(x2b + (size_t)rowb * HD1))[t * 2];
            ushort4 v2 = ((const ushort4*)(x2b + (size_t)rowb * HD1))[t * 2 + 1];
            float4 f0 = { bf2f(v.x), bf2f(v.y), bf2f(v.z), bf2f(v.w) };
            float4 f1 = { bf2f(v2.x), bf2f(v2.y), bf2f(v2.z), bf2f(v2.w) };
            ((float4*)sX)[t * 2] = f0;
            ((float4*)sX)[t * 2 + 1] = f1;
        }
        __syncthreads();
        float acc = 0.f;
        #pragma unroll 8
        for (int k = 0; k < HD1; k++)
            acc += sX[r * HD1 + k] * sW[k * NC + c];
        int row = rowb + r;
        h2e[(size_t)row * 32 + c] = f2bf(acc);
        float pe = acc * a2, pr = acc * r2;
        #pragma unroll
        for (int d = 1; d < 16; d <<= 1){ pe += __shfl_xor(pe, d); pr += __shfl_xor(pr, d); }
        if (c == 0){
            *(float*)(h2e + (size_t)row * 32 + 16) = pe * LOG2E;
            er2[row] = pr * LOG2E;
        }
    }
}

// ---------------- Layer-2 aggregation + bias + log_softmax ----------------

__global__ void __launch_bounds__(256) k_agg2(const int* __restrict__ off, const int* __restrict__ csr_src,
                                              const float* __restrict__ er2,
                                              const unsigned short* __restrict__ h2e, const float* __restrict__ b2,
                                              float* __restrict__ out){
    int t = threadIdx.x;
    int sub = t >> 4;          // 16 nodes per block
    int c = t & 15;
    int n = blockIdx.x * 16 + sub;
    if (n >= N_NODES) return;
    int jb = off[n], je = off[n + 1];
    float er = er2[n];
    float accA = 0.f, accB = 0.f, wsA = 0.f, wsB = 0.f;
    int j = jb;
    #pragma unroll 2
    for (; j + 1 < je; j += 2){
        int s0 = csr_src[j];
        int s1 = csr_src[j + 1];
        const unsigned short* r0 = h2e + (size_t)s0 * 32;
        const unsigned short* r1 = h2e + (size_t)s1 * 32;
        float el0 = *(const float*)(r0 + 16);
        float el1 = *(const float*)(r1 + 16);
        float w0 = __builtin_amdgcn_exp2f(leaky(el0 + er));
        float w1 = __builtin_amdgcn_exp2f(leaky(el1 + er));
        float v0 = bf2f(r0[c]);
        float v1 = bf2f(r1[c]);
        wsA += w0; accA += w0 * v0;
        wsB += w1; accB += w1 * v1;
    }
    if (j < je){
        int s0 = csr_src[j];
        const unsigned short* r0 = h2e + (size_t)s0 * 32;
        float el0 = *(const float*)(r0 + 16);
        float w0 = __builtin_amdgcn_exp2f(leaky(el0 + er));
        wsA += w0; accA += w0 * bf2f(r0[c]);
    }
    float acc = accA + accB, wsum = wsA + wsB;
    float o = (je > jb) ? acc / wsum : 0.f;
    o += b2[c];
    // log_softmax over the 16 classes (16-lane group)
    float m = o;
    #pragma unroll
    for (int d = 1; d < 16; d <<= 1) m = fmaxf(m, __shfl_xor(m, d));
    float ex = __expf(o - m);
    #pragma unroll
    for (int d = 1; d < 16; d <<= 1) ex += __shfl_xor(ex, d);
    out[(size_t)n * NC + c] = o - m - __logf(ex);
}

// ---------------- launch ----------------

extern "C" void kernel_launch(void* const* d_in, const int* in_sizes, int n_in,
                              void* d_out, int out_size, void* d_ws, size_t ws_size,
                              hipStream_t stream){
    const float* feat = (const float*)d_in[0];
    const int*   src  = (const int*)d_in[1];
    const int*   dst  = (const int*)d_in[2];
    const float* W1   = (const float*)d_in[3];
    const float* al1  = (const float*)d_in[4];
    const float* ar1  = (const float*)d_in[5];
    const float* b1   = (const float*)d_in[6];
    const float* W2   = (const float*)d_in[7];
    const float* al2  = (const float*)d_in[8];
    const float* ar2  = (const float*)d_in[9];
    const float* b2   = (const float*)d_in[10];
    float* out = (float*)d_out;

    char* w = (char*)d_ws;
    auto alloc = [&](size_t bytes) -> char* {
        char* p = w;
        w += (bytes + 255) & ~(size_t)255;
        return p;
    };
    int*   off      = (int*)alloc((size_t)(N_NODES + 1) * 4);
    int*   csr_src  = (int*)alloc((size_t)N_EDGES * 4);
    unsigned long long* pairs = (unsigned long long*)alloc((size_t)N_EDGES * 8);
    int*   bucketPart   = (int*)alloc((size_t)P1_BLOCKS * NBKT * 4);
    int*   bucketBase   = (int*)alloc((size_t)(NBKT + 1) * 4);
    int*   bucketCursor = (int*)alloc((size_t)(NBKT + 1) * 4);
    unsigned char*  h1f8 = (unsigned char*)alloc((size_t)N_NODES * HD1);
    unsigned short* el1b = (unsigned short*)alloc((size_t)N_NODES * HEADS * 2);
    float* er1v    = (float*)alloc((size_t)N_NODES * HEADS * 4);
    unsigned short* x2b = (unsigned short*)alloc((size_t)N_NODES * HD1 * 2);
    unsigned short* h2e = (unsigned short*)alloc((size_t)N_NODES * 64);
    float* er2v    = (float*)alloc((size_t)N_NODES * 4);
    short* WTH     = (short*)alloc((size_t)F_IN * HD1 * 2);

    // CSR build (bucketed two-pass; p1hist also performs the W1 split)
    k_p1hist<<<P1_BLOCKS + SPLITW_BLOCKS, 256, 0, stream>>>(dst, bucketPart, W1, WTH);
    k_p1scan<<<1, 256, 0, stream>>>(bucketPart, bucketBase, bucketCursor, off);
    k_p1bin<<<P1_BLOCKS, 256, 0, stream>>>(src, dst, bucketPart, bucketCursor, pairs);
    k_p2place<<<NBKT, 256, 0, stream>>>(pairs, bucketBase, off, csr_src);

    // Layer 1 compute
    k_gemm1m<<<(N_NODES + 255) / 256, 512, 0, stream>>>(feat, WTH, h1f8);
    k_attn1<<<(N_NODES * HEADS + 255) / 256, 256, 0, stream>>>(h1f8, al1, ar1, el1b, er1v);

    // Layer-1 aggregation
    k_agg1<<<(N_NODES + 3) / 4, 256, 0, stream>>>(off, csr_src, el1b, er1v, h1f8, b1, x2b);

    // Layer 2
    k_gemm2<<<1024, 256, 0, stream>>>(x2b, W2, al2, ar2, h2e, er2v);
    k_agg2<<<(N_NODES + 15) / 16, 256, 0, stream>>>(off, csr_src, er2v, h2e, b2, out);
}

// Round 18
// 189.961 us; speedup vs baseline: 1.2973x; 1.0768x over previous
//
#include <hip/hip_runtime.h>

#define N_NODES 100000
#define N_EDGES 1600000
#define F_IN 256
#define HD1 128   // HEADS*HID
#define HEADS 8
#define HID 16
#define NC 16
#define NEG_SLOPE 0.2f
#define LOG2E 1.44269504f

// ---- bucketed CSR build params ----
#define BKT_NODES 512
#define NBKT ((N_NODES + BKT_NODES - 1) / BKT_NODES)   // 196
#define P1_EPB 8192
#define P1_BLOCKS ((N_EDGES + P1_EPB - 1) / P1_EPB)    // 196
#define SPLITW_BLOCKS ((F_IN * HD1) / 256)             // 128
#define GEMM1_BLOCKS ((N_NODES + 255) / 256)           // 391
#define ATTN1_BLOCKS ((N_NODES * HEADS + 255) / 256)   // 3125

__device__ __forceinline__ float leaky(float x){ return x > 0.f ? x : NEG_SLOPE * x; }
__device__ __forceinline__ unsigned short f2bf(float f){
    unsigned u = __float_as_uint(f);
    u += 0x7fff + ((u >> 16) & 1);       // round-to-nearest-even
    return (unsigned short)(u >> 16);
}
__device__ __forceinline__ float bf2f(unsigned short s){
    return __uint_as_float((unsigned)s << 16);
}
__device__ __forceinline__ unsigned char f2fp8(float v){
    return (unsigned char)(__builtin_amdgcn_cvt_pk_fp8_f32(v, v, 0, false) & 0xff);
}
// hardware packed fp32->bf16 (RNE), 2 floats -> 1 dword
__device__ __forceinline__ unsigned cvtpk_bf16(float lo, float hi){
    unsigned r;
    asm("v_cvt_pk_bf16_f32 %0, %1, %2" : "=v"(r) : "v"(lo), "v"(hi));
    return r;
}

typedef __bf16 bf16x8 __attribute__((ext_vector_type(8)));
typedef short short8 __attribute__((ext_vector_type(8)));
typedef float f32x4 __attribute__((ext_vector_type(4)));
typedef float f32x2 __attribute__((ext_vector_type(2)));

// ---------------- CSR phase 1a: per-block hist (no atomics) + fused W1 split ----------------

__global__ void __launch_bounds__(256) k_p1hist(const int* __restrict__ dst, int* __restrict__ bucketPart,
                                                const float* __restrict__ W1, short* __restrict__ WTH){
    int t = threadIdx.x;
    int bid = blockIdx.x;
    if (bid >= P1_BLOCKS){
        // fused splitW: W1 -> bf16, transpose + XOR-swizzle
        int i = (bid - P1_BLOCKS) * 256 + t;
        int k = i >> 7, n = i & 127;
        int idx = n * 256 + (k ^ ((n & 7) << 3));
        WTH[idx] = (short)f2bf(W1[i]);
        return;
    }
    __shared__ int h[NBKT];
    for (int i = t; i < NBKT; i += 256) h[i] = 0;
    __syncthreads();
    int base = bid * P1_EPB;
    int m = min(P1_EPB, N_EDGES - base);
    for (int i = t; i < m; i += 256) atomicAdd(&h[(unsigned)dst[base + i] >> 9], 1);
    __syncthreads();
    for (int i = t; i < NBKT; i += 256) bucketPart[bid * NBKT + i] = h[i];
}

__global__ void __launch_bounds__(256) k_p1scan(const int* __restrict__ bucketPart,
                                                int* __restrict__ bucketBase, int* __restrict__ bucketCursor,
                                                int* __restrict__ off){
    __shared__ int sc[256];
    int t = threadIdx.x;
    int v = 0;
    if (t < NBKT)
        for (int b = 0; b < P1_BLOCKS; b++) v += bucketPart[b * NBKT + t];
    sc[t] = v; __syncthreads();
    for (int o = 1; o < 256; o <<= 1){
        int a = (t >= o) ? sc[t - o] : 0;
        __syncthreads();
        sc[t] += a;
        __syncthreads();
    }
    if (t < NBKT){
        int b = sc[t] - v;         // exclusive
        bucketBase[t] = b;
        bucketCursor[t] = b;
    }
    if (t == 0){ bucketBase[NBKT] = N_EDGES; off[N_NODES] = N_EDGES; }
}

// ---------------- fused dispatch: p1bin (blocks 0..195) || gemm1m (blocks 196..) ----------------
// Both roles use 512 threads; 68KB shared char buffer overlaid per role.
// p1bin depends on p1scan; gemm1m depends only on WTH (dispatch 1). Independent -> co-scheduled.

__device__ __forceinline__ short8 pack8(float4 f0, float4 f1){
    uint4 p;
    p.x = cvtpk_bf16(f0.x, f0.y);
    p.y = cvtpk_bf16(f0.z, f0.w);
    p.z = cvtpk_bf16(f1.x, f1.y);
    p.w = cvtpk_bf16(f1.z, f1.w);
    return __builtin_bit_cast(short8, p);
}

__global__ void __launch_bounds__(512, 4) k_bin_gemm(const int* __restrict__ src, const int* __restrict__ dst,
                                                     const int* __restrict__ bucketPart,
                                                     int* __restrict__ bucketCursor,
                                                     unsigned long long* __restrict__ pairs,
                                                     const float* __restrict__ feat,
                                                     const short* __restrict__ WTH,
                                                     unsigned char* __restrict__ h1f8){
    __shared__ __align__(16) char smem[69888];   // 68.25 KB
    int t = threadIdx.x;
    int bid = blockIdx.x;

    if (bid < P1_BLOCKS){
        // ---- p1bin role ----
        unsigned long long* pl = (unsigned long long*)smem;          // 64 KB
        int* h  = (int*)(smem + 65536);                              // NBKT
        int* dl = h + 256;                                           // NBKT
        int* sc = dl + 256;                                          // 256
        int v = (t < NBKT) ? bucketPart[bid * NBKT + t] : 0;
        if (t < 256) sc[t] = v;
        __syncthreads();
        for (int o = 1; o < 256; o <<= 1){
            int a = (t < 256 && t >= o) ? sc[t - o] : 0;
            __syncthreads();
            if (t < 256) sc[t] += a;
            __syncthreads();
        }
        if (t < NBKT){
            int ex = sc[t] - v;                        // local exclusive base
            int gb = v ? atomicAdd(&bucketCursor[t], v) : 0;
            dl[t] = gb - ex;
            h[t] = ex;                                 // running local cursor
        }
        __syncthreads();
        int base = bid * P1_EPB;
        int m = min(P1_EPB, N_EDGES - base);
        for (int i = t; i < m; i += 512){
            int d = dst[base + i], s = src[base + i];
            int b = (unsigned)d >> 9;
            int p = atomicAdd(&h[b], 1);
            pl[p] = ((unsigned long long)(unsigned)d << 32) | (unsigned)s;
        }
        __syncthreads();
        for (int i = t; i < m; i += 512){
            unsigned long long pr = pl[i];
            int b = (unsigned)(pr >> 32) >> 9;
            pairs[i + dl[b]] = pr;                     // sequential-run writes
        }
        return;
    }

    // ---- gemm1m role ----
    short* sWH = (short*)smem;   // 64 KB
    {
        const short8* gh = (const short8*)WTH;
        short8* sh = (short8*)sWH;
        for (int i = t; i < 4096; i += 512) sh[i] = gh[i];
    }
    __syncthreads();

    int wid = t >> 6, lane = t & 63;
    int m16 = lane & 15, kg = lane >> 4;
    int rowb = (bid - P1_BLOCKS) * 256 + wid * 32;

    f32x4 acc[2][8];
    #pragma unroll
    for (int a = 0; a < 2; a++)
        #pragma unroll
        for (int b = 0; b < 8; b++)
            acc[a][b] = (f32x4){0.f, 0.f, 0.f, 0.f};

    int r0 = rowb + m16;       if (r0 > N_NODES - 1) r0 = N_NODES - 1;
    int r1 = rowb + 16 + m16;  if (r1 > N_NODES - 1) r1 = N_NODES - 1;
    const float* fp0 = feat + (size_t)r0 * F_IN;
    const float* fp1 = feat + (size_t)r1 * F_IN;

    #pragma unroll
    for (int ks = 0; ks < 8; ks++){
        int kbase = ks * 32 + kg * 8;
        short8 a0, a1;
        {
            const float4* p = (const float4*)(fp0 + kbase);
            a0 = pack8(p[0], p[1]);
        }
        {
            const float4* p = (const float4*)(fp1 + kbase);
            a1 = pack8(p[0], p[1]);
        }
        bf16x8 AH0 = __builtin_bit_cast(bf16x8, a0);
        bf16x8 AH1 = __builtin_bit_cast(bf16x8, a1);
        __builtin_amdgcn_s_setprio(1);
        #pragma unroll
        for (int c = 0; c < 8; c++){
            int n = (c << 4) + m16;
            int kk = kbase ^ ((n & 7) << 3);
            bf16x8 bh = __builtin_bit_cast(bf16x8, *(const short8*)(sWH + n * 256 + kk));
            acc[0][c] = __builtin_amdgcn_mfma_f32_16x16x32_bf16(AH0, bh, acc[0][c], 0, 0, 0);
            acc[1][c] = __builtin_amdgcn_mfma_f32_16x16x32_bf16(AH1, bh, acc[1][c], 0, 0, 0);
        }
        __builtin_amdgcn_s_setprio(0);
    }

    #pragma unroll
    for (int rf = 0; rf < 2; rf++){
        #pragma unroll
        for (int c = 0; c < 8; c++){
            #pragma unroll
            for (int r = 0; r < 4; r++){
                int row = rowb + rf * 16 + kg * 4 + r;
                if (row < N_NODES){
                    int col = c * 16 + m16;
                    h1f8[(size_t)row * HD1 + col] = f2fp8(acc[rf][c][r]);
                }
            }
        }
    }
}

// ---------------- fused dispatch: p2place (blocks 0..195) || attn1 (rest) ----------------

__global__ void __launch_bounds__(256) k_place_attn(const unsigned long long* __restrict__ pairs,
                                                    const int* __restrict__ bucketBase,
                                                    int* __restrict__ off, int* __restrict__ csr_src,
                                                    const unsigned char* __restrict__ h1f8,
                                                    const float* __restrict__ al1, const float* __restrict__ ar1,
                                                    unsigned short* __restrict__ el1b, float* __restrict__ er1){
    int t = threadIdx.x;
    int bid = blockIdx.x;

    if (bid >= NBKT){
        // ---- attn1 role ----
        int i = (bid - NBKT) * 256 + t;
        if (i >= N_NODES * HEADS) return;
        int n = i >> 3, h = i & 7;
        uint4 hv = *(const uint4*)(h1f8 + (size_t)n * HD1 + h * HID);
        unsigned uu[4] = {hv.x, hv.y, hv.z, hv.w};
        float pe = 0.f, pr = 0.f;
        #pragma unroll
        for (int j = 0; j < 4; j++){
            unsigned u = uu[j];
            float x0 = __builtin_amdgcn_cvt_f32_fp8(u, 0);
            float x1 = __builtin_amdgcn_cvt_f32_fp8(u, 1);
            float x2 = __builtin_amdgcn_cvt_f32_fp8(u, 2);
            float x3 = __builtin_amdgcn_cvt_f32_fp8(u, 3);
            const float4 a = ((const float4*)(al1 + h * HID))[j];
            const float4 r = ((const float4*)(ar1 + h * HID))[j];
            pe += x0 * a.x + x1 * a.y + x2 * a.z + x3 * a.w;
            pr += x0 * r.x + x1 * r.y + x2 * r.z + x3 * r.w;
        }
        el1b[i] = f2bf(pe * LOG2E);
        er1[i] = pr * LOG2E;
        return;
    }

    // ---- p2place role ----
    __shared__ int degc[BKT_NODES];
    __shared__ int sc2[BKT_NODES];
    int b = bid;
    int node0 = b * BKT_NODES;
    int nmax = min(BKT_NODES, N_NODES - node0);
    int p0 = bucketBase[b], p1 = bucketBase[b + 1];
    int m = p1 - p0;
    for (int i = t; i < BKT_NODES; i += 256) degc[i] = 0;
    __syncthreads();
    for (int i = t; i < m; i += 256){
        int d = (int)(pairs[p0 + i] >> 32) - node0;
        atomicAdd(&degc[d], 1);
    }
    __syncthreads();
    for (int i = t; i < BKT_NODES; i += 256) sc2[i] = degc[i];
    __syncthreads();
    // Hillis-Steele inclusive scan over 512 with 256 threads
    for (int o = 1; o < BKT_NODES; o <<= 1){
        int i0 = t, i1 = t + 256;
        int a0 = (i0 >= o) ? sc2[i0 - o] : 0;
        int a1 = (i1 >= o) ? sc2[i1 - o] : 0;
        __syncthreads();
        sc2[i0] += a0; sc2[i1] += a1;
        __syncthreads();
    }
    for (int i = t; i < BKT_NODES; i += 256){
        int cur = p0 + sc2[i] - degc[i];           // global exclusive offset
        if (i < nmax) off[node0 + i] = cur;
        degc[i] = cur;                              // becomes global cursor
    }
    __syncthreads();
    for (int i = t; i < m; i += 256){
        unsigned long long pr = pairs[p0 + i];
        int d = (int)(pr >> 32) - node0;
        int pos = atomicAdd(&degc[d], 1);
        csr_src[pos] = (int)(unsigned)pr;          // random only within 32KB window
    }
}

// ---------------- Layer-1 aggregation: 1 wave/node, 16 lanes/edge, 4 edges/iter ----------------

__global__ void __launch_bounds__(256) k_agg1(const int* __restrict__ off, const int* __restrict__ csr_src,
                                              const unsigned short* __restrict__ el1b,
                                              const float* __restrict__ er1,
                                              const unsigned char* __restrict__ h1f8,
                                              const float* __restrict__ b1,
                                              unsigned short* __restrict__ x2b){
    int wid = threadIdx.x >> 6, lane = threadIdx.x & 63;
    int n = blockIdx.x * 4 + wid;
    if (n >= N_NODES) return;
    int jb = off[n], je = off[n + 1];
    int sub = lane >> 4;       // edge slot within quad (0..3)
    int q = lane & 15;         // column group: cols q*8 .. q*8+7
    int hh = q >> 1;           // head (2 lanes per head)
    float ern = er1[n * HEADS + hh];
    float a0=0.f,a1=0.f,a2=0.f,a3=0.f,a4=0.f,a5=0.f,a6=0.f,a7=0.f,wsum=0.f;

    #pragma unroll 4
    for (int j = jb; j < je; j += 4){
        int jj = j + sub;
        int jc = (jj < je) ? jj : je - 1;
        int s = csr_src[jc];
        float el = bf2f(el1b[s * HEADS + hh]);
        float wv = (jj < je) ? __builtin_amdgcn_exp2f(leaky(el + ern)) : 0.f;
        wsum += wv;
        uint2 u = *(const uint2*)(h1f8 + (((size_t)s) << 7) + (q << 3));
        f32x2 p0 = __builtin_amdgcn_cvt_pk_f32_fp8(u.x, 0);
        f32x2 p1 = __builtin_amdgcn_cvt_pk_f32_fp8(u.x, 1);
        f32x2 p2 = __builtin_amdgcn_cvt_pk_f32_fp8(u.y, 0);
        f32x2 p3 = __builtin_amdgcn_cvt_pk_f32_fp8(u.y, 1);
        a0 += wv * p0.x; a1 += wv * p0.y;
        a2 += wv * p1.x; a3 += wv * p1.y;
        a4 += wv * p2.x; a5 += wv * p2.y;
        a6 += wv * p3.x; a7 += wv * p3.y;
    }

    // reduce across the 4 edge-slots (lanes differing in bits 4,5)
    a0 += __shfl_xor(a0, 16); a0 += __shfl_xor(a0, 32);
    a1 += __shfl_xor(a1, 16); a1 += __shfl_xor(a1, 32);
    a2 += __shfl_xor(a2, 16); a2 += __shfl_xor(a2, 32);
    a3 += __shfl_xor(a3, 16); a3 += __shfl_xor(a3, 32);
    a4 += __shfl_xor(a4, 16); a4 += __shfl_xor(a4, 32);
    a5 += __shfl_xor(a5, 16); a5 += __shfl_xor(a5, 32);
    a6 += __shfl_xor(a6, 16); a6 += __shfl_xor(a6, 32);
    a7 += __shfl_xor(a7, 16); a7 += __shfl_xor(a7, 32);
    wsum += __shfl_xor(wsum, 16); wsum += __shfl_xor(wsum, 32);

    if (sub == 0){
        float inv = (je > jb) ? 1.f / wsum : 0.f;
        float o0 = a0*inv, o1 = a1*inv, o2 = a2*inv, o3 = a3*inv;
        float o4 = a4*inv, o5 = a5*inv, o6 = a6*inv, o7 = a7*inv;
        float4 bv0 = *(const float4*)(b1 + (q << 3));
        float4 bv1 = *(const float4*)(b1 + (q << 3) + 4);
        o0 += bv0.x; o1 += bv0.y; o2 += bv0.z; o3 += bv0.w;
        o4 += bv1.x; o5 += bv1.y; o6 += bv1.z; o7 += bv1.w;
        o0 = o0 > 0.f ? o0 : __expf(o0) - 1.f;
        o1 = o1 > 0.f ? o1 : __expf(o1) - 1.f;
        o2 = o2 > 0.f ? o2 : __expf(o2) - 1.f;
        o3 = o3 > 0.f ? o3 : __expf(o3) - 1.f;
        o4 = o4 > 0.f ? o4 : __expf(o4) - 1.f;
        o5 = o5 > 0.f ? o5 : __expf(o5) - 1.f;
        o6 = o6 > 0.f ? o6 : __expf(o6) - 1.f;
        o7 = o7 > 0.f ? o7 : __expf(o7) - 1.f;
        uint4 ov;
        ov.x = cvtpk_bf16(o0, o1);
        ov.y = cvtpk_bf16(o2, o3);
        ov.z = cvtpk_bf16(o4, o5);
        ov.w = cvtpk_bf16(o6, o7);
        *(uint4*)(x2b + (size_t)n * HD1 + (q << 3)) = ov;
    }
}

// ---------------- GEMM2: h2e rows = [16 x bf16 h2 | fp32 el2 | pad] (64B) ----------------

__global__ void __launch_bounds__(256) k_gemm2(const unsigned short* __restrict__ x2b, const float* __restrict__ W2,
                                               const float* __restrict__ al2, const float* __restrict__ ar2,
                                               unsigned short* __restrict__ h2e, float* __restrict__ er2){
    __shared__ float sW[HD1 * NC];   // 8 KB
    __shared__ float sX[16 * HD1];   // 8 KB
    int t = threadIdx.x;
    for (int i = t; i < (HD1 * NC) / 4; i += 256)
        ((float4*)sW)[i] = ((const float4*)W2)[i];
    int r = t >> 4, c = t & 15;
    float a2 = al2[c], r2 = ar2[c];
    for (int g = blockIdx.x; g * 16 < N_NODES; g += gridDim.x){
        int rowb = g * 16;
        __syncthreads();
        {
            ushort4 v = ((const ushort4*)(x2b + (size_t)rowb * HD1))[t * 2];
            ushort4 v2 = ((const ushort4*)(x2b + (size_t)rowb * HD1))[t * 2 + 1];
            float4 f0 = { bf2f(v.x), bf2f(v.y), bf2f(v.z), bf2f(v.w) };
            float4 f1 = { bf2f(v2.x), bf2f(v2.y), bf2f(v2.z), bf2f(v2.w) };
            ((float4*)sX)[t * 2] = f0;
            ((float4*)sX)[t * 2 + 1] = f1;
        }
        __syncthreads();
        float acc = 0.f;
        #pragma unroll 8
        for (int k = 0; k < HD1; k++)
            acc += sX[r * HD1 + k] * sW[k * NC + c];
        int row = rowb + r;
        h2e[(size_t)row * 32 + c] = f2bf(acc);
        float pe = acc * a2, pr = acc * r2;
        #pragma unroll
        for (int d = 1; d < 16; d <<= 1){ pe += __shfl_xor(pe, d); pr += __shfl_xor(pr, d); }
        if (c == 0){
            *(float*)(h2e + (size_t)row * 32 + 16) = pe * LOG2E;
            er2[row] = pr * LOG2E;
        }
    }
}

// ---------------- Layer-2 aggregation + bias + log_softmax ----------------

__global__ void __launch_bounds__(256) k_agg2(const int* __restrict__ off, const int* __restrict__ csr_src,
                                              const float* __restrict__ er2,
                                              const unsigned short* __restrict__ h2e, const float* __restrict__ b2,
                                              float* __restrict__ out){
    int t = threadIdx.x;
    int sub = t >> 4;          // 16 nodes per block
    int c = t & 15;
    int n = blockIdx.x * 16 + sub;
    if (n >= N_NODES) return;
    int jb = off[n], je = off[n + 1];
    float er = er2[n];
    float accA = 0.f, accB = 0.f, wsA = 0.f, wsB = 0.f;
    int j = jb;
    #pragma unroll 2
    for (; j + 1 < je; j += 2){
        int s0 = csr_src[j];
        int s1 = csr_src[j + 1];
        const unsigned short* r0 = h2e + (size_t)s0 * 32;
        const unsigned short* r1 = h2e + (size_t)s1 * 32;
        float el0 = *(const float*)(r0 + 16);
        float el1 = *(const float*)(r1 + 16);
        float w0 = __builtin_amdgcn_exp2f(leaky(el0 + er));
        float w1 = __builtin_amdgcn_exp2f(leaky(el1 + er));
        float v0 = bf2f(r0[c]);
        float v1 = bf2f(r1[c]);
        wsA += w0; accA += w0 * v0;
        wsB += w1; accB += w1 * v1;
    }
    if (j < je){
        int s0 = csr_src[j];
        const unsigned short* r0 = h2e + (size_t)s0 * 32;
        float el0 = *(const float*)(r0 + 16);
        float w0 = __builtin_amdgcn_exp2f(leaky(el0 + er));
        wsA += w0; accA += w0 * bf2f(r0[c]);
    }
    float acc = accA + accB, wsum = wsA + wsB;
    float o = (je > jb) ? acc / wsum : 0.f;
    o += b2[c];
    // log_softmax over the 16 classes (16-lane group)
    float m = o;
    #pragma unroll
    for (int d = 1; d < 16; d <<= 1) m = fmaxf(m, __shfl_xor(m, d));
    float ex = __expf(o - m);
    #pragma unroll
    for (int d = 1; d < 16; d <<= 1) ex += __shfl_xor(ex, d);
    out[(size_t)n * NC + c] = o - m - __logf(ex);
}

// ---------------- launch ----------------

extern "C" void kernel_launch(void* const* d_in, const int* in_sizes, int n_in,
                              void* d_out, int out_size, void* d_ws, size_t ws_size,
                              hipStream_t stream){
    const float* feat = (const float*)d_in[0];
    const int*   src  = (const int*)d_in[1];
    const int*   dst  = (const int*)d_in[2];
    const float* W1   = (const float*)d_in[3];
    const float* al1  = (const float*)d_in[4];
    const float* ar1  = (const float*)d_in[5];
    const float* b1   = (const float*)d_in[6];
    const float* W2   = (const float*)d_in[7];
    const float* al2  = (const float*)d_in[8];
    const float* ar2  = (const float*)d_in[9];
    const float* b2   = (const float*)d_in[10];
    float* out = (float*)d_out;

    char* w = (char*)d_ws;
    auto alloc = [&](size_t bytes) -> char* {
        char* p = w;
        w += (bytes + 255) & ~(size_t)255;
        return p;
    };
    int*   off      = (int*)alloc((size_t)(N_NODES + 1) * 4);
    int*   csr_src  = (int*)alloc((size_t)N_EDGES * 4);
    unsigned long long* pairs = (unsigned long long*)alloc((size_t)N_EDGES * 8);
    int*   bucketPart   = (int*)alloc((size_t)P1_BLOCKS * NBKT * 4);
    int*   bucketBase   = (int*)alloc((size_t)(NBKT + 1) * 4);
    int*   bucketCursor = (int*)alloc((size_t)(NBKT + 1) * 4);
    unsigned char*  h1f8 = (unsigned char*)alloc((size_t)N_NODES * HD1);
    unsigned short* el1b = (unsigned short*)alloc((size_t)N_NODES * HEADS * 2);
    float* er1v    = (float*)alloc((size_t)N_NODES * HEADS * 4);
    unsigned short* x2b = (unsigned short*)alloc((size_t)N_NODES * HD1 * 2);
    unsigned short* h2e = (unsigned short*)alloc((size_t)N_NODES * 64);
    float* er2v    = (float*)alloc((size_t)N_NODES * 4);
    short* WTH     = (short*)alloc((size_t)F_IN * HD1 * 2);

    // 1) per-block hist + W1 split
    k_p1hist<<<P1_BLOCKS + SPLITW_BLOCKS, 256, 0, stream>>>(dst, bucketPart, W1, WTH);
    // 2) bucket scan
    k_p1scan<<<1, 256, 0, stream>>>(bucketPart, bucketBase, bucketCursor, off);
    // 3) bin edges || GEMM1 (independent, co-scheduled)
    k_bin_gemm<<<P1_BLOCKS + GEMM1_BLOCKS, 512, 0, stream>>>(src, dst, bucketPart, bucketCursor, pairs,
                                                             feat, WTH, h1f8);
    // 4) place CSR || attn1 (independent, co-scheduled)
    k_place_attn<<<NBKT + ATTN1_BLOCKS, 256, 0, stream>>>(pairs, bucketBase, off, csr_src,
                                                          h1f8, al1, ar1, el1b, er1v);
    // 5) Layer-1 aggregation
    k_agg1<<<(N_NODES + 3) / 4, 256, 0, stream>>>(off, csr_src, el1b, er1v, h1f8, b1, x2b);
    // 6) Layer 2 GEMM
    k_gemm2<<<1024, 256, 0, stream>>>(x2b, W2, al2, ar2, h2e, er2v);
    // 7) Layer-2 aggregation + log_softmax
    k_agg2<<<(N_NODES + 15) / 16, 256, 0, stream>>>(off, csr_src, er2v, h2e, b2, out);
}